// Round 7
// baseline (182.227 us; speedup 1.0000x reference)
//
#include <hip/hip_runtime.h>
#include <math.h>

typedef _Float16 f16;
typedef __attribute__((ext_vector_type(8))) _Float16 f16x8;
typedef __attribute__((ext_vector_type(4))) _Float16 f16x4;
typedef __attribute__((ext_vector_type(4))) float f32x4;

#define NH 12
#define HDIM 64
#define NTOK 197
#define EDIM 768
#define NB 64
#define MROWS (NB*NTOK)   // 12608

// ---------------------------------------------------------------------------
// x [12608x768] f32 -> f16.
// ---------------------------------------------------------------------------
__global__ __launch_bounds__(256) void convert_x(
    const float* __restrict__ x, f16* __restrict__ xh)
{
    int idx = blockIdx.x * 256 + threadIdx.x;
    const float4* s = (const float4*)x + (size_t)idx * 2;
    float4 a = s[0], b = s[1];
    f16x8 h;
    h[0]=(f16)a.x; h[1]=(f16)a.y; h[2]=(f16)a.z; h[3]=(f16)a.w;
    h[4]=(f16)b.x; h[5]=(f16)b.y; h[6]=(f16)b.z; h[7]=(f16)b.w;
    *(f16x8*)(xh + (size_t)idx * 8) = h;
}

// ---------------------------------------------------------------------------
// LDS-tiled transpose + f16: wT[n][k] = (f16)w[k][n].
// ---------------------------------------------------------------------------
__global__ __launch_bounds__(256) void transpose_w(
    const float* __restrict__ wq, const float* __restrict__ wk,
    const float* __restrict__ wv, const float* __restrict__ wp,
    f16* __restrict__ wqkvT, f16* __restrict__ wpT)
{
    __shared__ float T[64][65];
    int m = blockIdx.z;
    const float* src = (m==0)?wq:(m==1)?wk:(m==2)?wv:wp;
    int k0 = blockIdx.x * 64, n0 = blockIdx.y * 64;
    int cidx = threadIdx.x & 63, r4 = threadIdx.x >> 6;
#pragma unroll
    for (int rr = 0; rr < 16; ++rr) {
        int kl = rr*4 + r4;
        T[kl][cidx] = src[(size_t)(k0+kl)*EDIM + n0 + cidx];
    }
    __syncthreads();
    f16* dst = (m < 3) ? (wqkvT + (size_t)m*EDIM*EDIM) : wpT;
#pragma unroll
    for (int rr = 0; rr < 16; ++rr) {
        int nl = rr*4 + r4;
        dst[(size_t)(n0+nl)*EDIM + k0 + cidx] = (f16)T[cidx][nl];
    }
}

// ---------------------------------------------------------------------------
// f16 MFMA GEMM with global_load_lds staging (m97 structure) + XCD swizzle.
// C[M x N] = A[M x 768] @ Bt[N x 768]^T, 128x128 tile, BK=64, 4 waves.
// LDS linear dest; global SOURCE col pre-swizzled by ((row&7)<<3) so the
// XOR-swizzled ds_read_b128 fragment loads decode to the true layout (T2+#21).
// Flattened 1-D grid, bijective XCD-chunk swizzle (m204), m-band-major so
// each XCD chunk keeps ~13 A-panels + all of B resident in its private L2.
// ---------------------------------------------------------------------------
__device__ __forceinline__ void gload16(const f16* g, f16* lds_base) {
    __builtin_amdgcn_global_load_lds(
        (const __attribute__((address_space(1))) void*)g,
        (__attribute__((address_space(3))) void*)lds_base, 16, 0, 0);
}

__global__ __launch_bounds__(256) void gemm_h(
    const f16* __restrict__ A, const f16* __restrict__ Bt,
    f16* __restrict__ q_o, f16* __restrict__ k_o, f16* __restrict__ v_o,
    float* __restrict__ p_o, const float* __restrict__ bias, int mode, int nxb)
{
    __shared__ f16 As[128*64];
    __shared__ f16 Bs[128*64];

    const int tid = threadIdx.x;
    const int l  = tid & 63;
    const int w  = tid >> 6;
    const int lr = l & 15, lq = l >> 4;
    const int wr = w >> 1, wc = w & 1;

    // ---- XCD-aware bijective swizzle (m204) ----
    const int nwg  = gridDim.x;
    const int orig = blockIdx.x;
    const int xcd  = orig & 7;
    const int qc   = nwg >> 3, rc = nwg & 7;
    const int wgid = (xcd < rc ? xcd*(qc+1) : rc*(qc+1) + (xcd-rc)*qc) + (orig >> 3);
    const int mband = wgid / nxb, nband = wgid - mband*nxb;
    const int m0 = mband << 7, n0 = nband << 7;

    // ---- staging geometry: lane covers 16B; row8 = l>>3, c8 = (l&7)*8 ----
    // source col = c8 ^ ((row&7)<<3) = (((l&7) ^ (l>>3)) << 3)
    const int scol = (((l & 7) ^ (l >> 3)) << 3);
    const f16* aG[4]; const f16* bG[4];
    f16* aL[4]; f16* bL[4];
#pragma unroll
    for (int p = 0; p < 4; ++p) {
        int rt = (w*4 + p)*8 + (l >> 3);
        int ra = m0 + rt; if (ra >= MROWS) ra = MROWS - 1;
        aG[p] = A  + (size_t)ra * EDIM + scol;
        bG[p] = Bt + (size_t)(n0 + rt) * EDIM + scol;
        aL[p] = &As[(w*4 + p) * 512];
        bL[p] = &Bs[(w*4 + p) * 512];
    }

    f32x4 acc[4][4];
#pragma unroll
    for (int mt = 0; mt < 4; ++mt)
#pragma unroll
        for (int nt = 0; nt < 4; ++nt) {
            acc[mt][nt][0]=0.f; acc[mt][nt][1]=0.f;
            acc[mt][nt][2]=0.f; acc[mt][nt][3]=0.f;
        }

    for (int kt = 0; kt < 12; ++kt) {
        const int ko = kt * 64;
#pragma unroll
        for (int p = 0; p < 4; ++p) {
            gload16(aG[p] + ko, aL[p]);
            gload16(bG[p] + ko, bL[p]);
        }
        __syncthreads();           // compiler drains vmcnt before barrier
#pragma unroll
        for (int ks = 0; ks < 2; ++ks) {
            const int kb = ks*32 + lq*8;
            f16x8 af[4], bf[4];
#pragma unroll
            for (int mt = 0; mt < 4; ++mt) {
                int Ra = wr*64 + mt*16 + lr;
                af[mt] = *(const f16x8*)&As[Ra*64 + (kb ^ ((Ra&7)<<3))];
                int Rb = wc*64 + mt*16 + lr;
                bf[mt] = *(const f16x8*)&Bs[Rb*64 + (kb ^ ((Rb&7)<<3))];
            }
#pragma unroll
            for (int mt = 0; mt < 4; ++mt)
#pragma unroll
                for (int nt = 0; nt < 4; ++nt)
                    acc[mt][nt] = __builtin_amdgcn_mfma_f32_16x16x32_f16(
                        af[mt], bf[nt], acc[mt][nt], 0, 0, 0);
        }
        __syncthreads();           // protect LDS before next stage
    }

    if (mode == 0) {
        const int mat   = n0 / EDIM;
        const int hbase = ((n0 % EDIM) >> 6) + wc;
        f16* dst = (mat == 0) ? q_o : (mat == 1) ? k_o : v_o;
#pragma unroll
        for (int mt = 0; mt < 4; ++mt)
#pragma unroll
            for (int rg = 0; rg < 4; ++rg) {
                int R = m0 + wr*64 + mt*16 + lq*4 + rg;
                if (R < MROWS) {
                    int bb = R / NTOK, nn = R - bb * NTOK;
                    f16* base = dst + (((size_t)(bb*NH + hbase))*NTOK + nn) * HDIM;
#pragma unroll
                    for (int nt = 0; nt < 4; ++nt)
                        base[nt*16 + lr] = (f16)acc[mt][nt][rg];
                }
            }
    } else {
#pragma unroll
        for (int mt = 0; mt < 4; ++mt)
#pragma unroll
            for (int rg = 0; rg < 4; ++rg) {
                int R = m0 + wr*64 + mt*16 + lq*4 + rg;
                if (R < MROWS) {
                    float* base = p_o + (size_t)R * EDIM + n0 + wc*64;
#pragma unroll
                    for (int nt = 0; nt < 4; ++nt) {
                        int c = nt*16 + lr;
                        base[c] = acc[mt][nt][rg] + bias[n0 + wc*64 + c];
                    }
                }
            }
    }
}

// ---------------------------------------------------------------------------
// MFMA fused attention v3 (unchanged from round 6).
// ---------------------------------------------------------------------------
#define SKE 104
#define SVT 320
#define SGT 232
#define SWS 72

__device__ __forceinline__ void wfence() {
    asm volatile("s_waitcnt lgkmcnt(0)" ::: "memory");
    __builtin_amdgcn_sched_barrier(0);
    __builtin_amdgcn_wave_barrier();
}

__device__ __forceinline__ unsigned div14(unsigned n) { return (n * 4682u) >> 16; }  // exact n<=206

__global__ __launch_bounds__(768, 1) void attn_mfma(
    const f16* __restrict__ q_ws, const f16* __restrict__ k_ws,
    const f16* __restrict__ v_ws,
    const float* __restrict__ rkv, const float* __restrict__ rkh,
    const float* __restrict__ rvv, const float* __restrict__ rvh,
    f16* __restrict__ o_ws)
{
    __shared__ f16 Kle[272*SKE];
    __shared__ f16 Vt[64*SVT];
    __shared__ f16 Gt[32*SGT];
    __shared__ f16 WSh[12*16*SWS];

    const int tid = threadIdx.x;
    const int w = tid >> 6, l = tid & 63;
    const int lr = l & 15, lq = l >> 4;
    const int bh = blockIdx.x;
    const int b = bh / NH, h = bh - b * NH;
    const f16* Qp = q_ws + (size_t)bh * NTOK * HDIM;
    const f16* Kp = k_ws + (size_t)bh * NTOK * HDIM;
    const f16* Vp = v_ws + (size_t)bh * NTOK * HDIM;
    f16* wsh = &WSh[w * 16 * SWS];

    for (int idx = tid; idx < 272*13; idx += 768) {
        int row = idx / 13, c = idx - row*13;
        int c8 = c << 3;
        f16x8 hv;
#pragma unroll
        for (int e = 0; e < 8; ++e) hv[e] = (f16)0.f;
        if (c < 8) {
            if (row < NTOK) {
                hv = *(const f16x8*)(Kp + row*64 + c8);
            } else if (row >= 208 && row < 238) {
                const float* src = rkv + (row-208)*64 + c8;
                float4 a = *(const float4*)src, d = *(const float4*)(src+4);
                hv[0]=(f16)a.x; hv[1]=(f16)a.y; hv[2]=(f16)a.z; hv[3]=(f16)a.w;
                hv[4]=(f16)d.x; hv[5]=(f16)d.y; hv[6]=(f16)d.z; hv[7]=(f16)d.w;
            } else if (row >= 240 && row < 270) {
                const float* src = rkh + (row-240)*64 + c8;
                float4 a = *(const float4*)src, d = *(const float4*)(src+4);
                hv[0]=(f16)a.x; hv[1]=(f16)a.y; hv[2]=(f16)a.z; hv[3]=(f16)a.w;
                hv[4]=(f16)d.x; hv[5]=(f16)d.y; hv[6]=(f16)d.z; hv[7]=(f16)d.w;
            }
        } else if (c < 12 && row < 208) {
            int gbase = (c - 8) << 3;
            if (row == 0) {
#pragma unroll
                for (int e = 0; e < 8; ++e) {
                    int g = gbase + e;
                    hv[e] = (g == 14 || g == 30) ? (f16)1.f : (f16)0.f;
                }
            } else if (row <= 196) {
                int rm = row - 1;
                int gv = (int)div14((unsigned)rm);
                int gh = rm - gv*14;
#pragma unroll
                for (int e = 0; e < 8; ++e) {
                    int g = gbase + e;
                    hv[e] = (g == gv || g == 16 + gh) ? (f16)1.f : (f16)0.f;
                }
            }
        }
        *(f16x8*)&Kle[row*SKE + c8] = hv;
    }

    for (int idx = tid; idx < 8*SVT; idx += 768) {
        int dlow = idx & 7, k = idx >> 3;
        int kx = k ^ (dlow << 3);
        bool isV = (k < NTOK), isA = (k >= 208 && k < 238), isB = (k >= 238 && k < 268);
#pragma unroll
        for (int e = 0; e < 8; ++e) {
            int d = (e << 3) + dlow;
            f16 val = (f16)0.f;
            if (isV)      val = Vp[k*64 + d];
            else if (isA) val = (f16)rvv[(k-208)*64 + d];
            else if (isB) val = (f16)rvh[(k-238)*64 + d];
            Vt[d*SVT + kx] = val;
        }
    }

    for (int idx = tid; idx < 32*29; idx += 768) {
        int g = idx / 29, c = idx - g*29, c8 = c << 3;
        f16x8 hv;
#pragma unroll
        for (int e = 0; e < 8; ++e) hv[e] = (f16)0.f;
        if (g < 14 || (g >= 16 && g < 30)) {
#pragma unroll
            for (int e = 0; e < 8; ++e) {
                int j = c8 + e;
                if (j >= 1 && j <= 196) {
                    int jm = j - 1;
                    int gv = (int)div14((unsigned)jm);
                    int gh = jm - gv*14;
                    if ((g < 14 && gv == g) || (g >= 16 && gh == g - 16))
                        hv[e] = (f16)1.f;
                }
            }
        }
        *(f16x8*)&Gt[g*SGT + c8] = hv;
    }
    __syncthreads();

    const int src0 = ((l >> 4) & 1) * 32 + lr;
    const int src1 = src0 + 16;

    for (int tt = w; tt < 13; tt += 12) {
        const int i0 = tt * 16;
        const int iq = i0 + lr;
        const int iqc = (iq > 196) ? 196 : iq;
        const f16* qsrc = Qp + iqc*64 + lq*8;
        f16x8 qf0 = *(const f16x8*)qsrc;
        f16x8 qf1 = *(const f16x8*)(qsrc + 32);

        __builtin_amdgcn_s_setprio(1);
        f32x4 pacc[4];
#pragma unroll
        for (int ct = 0; ct < 4; ++ct) {
            f32x4 a; a[0]=0.f; a[1]=0.f; a[2]=0.f; a[3]=0.f;
            const int krow = (13+ct)*16 + lr;
            f16x8 kf0 = *(f16x8*)&Kle[krow*SKE + lq*8];
            f16x8 kf1 = *(f16x8*)&Kle[krow*SKE + 32 + lq*8];
            a = __builtin_amdgcn_mfma_f32_16x16x32_f16(kf0, qf0, a, 0, 0, 0);
            a = __builtin_amdgcn_mfma_f32_16x16x32_f16(kf1, qf1, a, 0, 0, 0);
            pacc[ct] = a;
        }
        __builtin_amdgcn_s_setprio(0);
#pragma unroll
        for (int ct = 0; ct < 4; ++ct)
#pragma unroll
            for (int rg = 0; rg < 4; ++rg)
                wsh[lr*SWS + ct*16 + lq*4 + rg] = (f16)pacc[ct][rg];
        wfence();

        int id_ = 0, ih_ = 0;
        const bool qcls = (iq == 0);
        if (iq > 0) { unsigned v = div14((unsigned)(iq-1)); id_ = (int)v; ih_ = (iq-1) - (int)v*14; }
        f16x8 qcf;
#pragma unroll
        for (int e = 0; e < 8; ++e) {
            int g = lq*8 + e;
            int toff;
            if (g < 14)       toff = qcls ? 0 : (g - id_ + 15);
            else if (g == 14) toff = 0;
            else if (g == 15) toff = 63;
            else if (g < 30)  toff = qcls ? 32 : (32 + (g-16) - ih_ + 15);
            else if (g == 30) toff = 32;
            else              toff = 63;
            qcf[e] = wsh[lr*SWS + toff];
        }

        f32x4 acc[13];
        __builtin_amdgcn_s_setprio(1);
#pragma unroll
        for (int ct = 0; ct < 13; ++ct) {
            f32x4 a; a[0]=0.f; a[1]=0.f; a[2]=0.f; a[3]=0.f;
            const int krow = ct*16 + lr;
            f16x8 kf0 = *(f16x8*)&Kle[krow*SKE + lq*8];
            f16x8 kf1 = *(f16x8*)&Kle[krow*SKE + 32 + lq*8];
            f16x8 gf  = *(f16x8*)&Kle[krow*SKE + 64 + lq*8];
            a = __builtin_amdgcn_mfma_f32_16x16x32_f16(kf0, qf0, a, 0, 0, 0);
            a = __builtin_amdgcn_mfma_f32_16x16x32_f16(kf1, qf1, a, 0, 0, 0);
            a = __builtin_amdgcn_mfma_f32_16x16x32_f16(gf,  qcf, a, 0, 0, 0);
            acc[ct] = a;
        }
        __builtin_amdgcn_s_setprio(0);

#pragma unroll
        for (int rg = 0; rg < 4; ++rg)
            if (lq*4 + rg > 4) acc[12][rg] = -1e30f;

        float m = -1e30f;
#pragma unroll
        for (int ct = 0; ct < 13; ++ct)
#pragma unroll
            for (int rg = 0; rg < 4; ++rg) m = fmaxf(m, acc[ct][rg]);
        m = fmaxf(m, __shfl_xor(m, 16));
        m = fmaxf(m, __shfl_xor(m, 32));
        const float C1 = 0.125f * 1.44269504088896f;
        const float nm = -m * C1;
        float ssum = 0.f;
#pragma unroll
        for (int ct = 0; ct < 13; ++ct)
#pragma unroll
            for (int rg = 0; rg < 4; ++rg) {
                float p = exp2f(fmaf(acc[ct][rg], C1, nm));
                acc[ct][rg] = p; ssum += p;
            }
        ssum += __shfl_xor(ssum, 16);
        ssum += __shfl_xor(ssum, 32);
        const float inv = 1.f / ssum;
        const float pn00 = acc[0][0] * inv;

        unsigned pk[13][2];
#pragma unroll
        for (int ct = 0; ct < 13; ++ct) {
            union { f16x4 hh; unsigned u[2]; } t;
            t.hh[0] = (f16)(acc[ct][0] * inv);
            t.hh[1] = (f16)(acc[ct][1] * inv);
            t.hh[2] = (f16)(acc[ct][2] * inv);
            t.hh[3] = (f16)(acc[ct][3] * inv);
            pk[ct][0] = t.u[0]; pk[ct][1] = t.u[1];
        }

        f16x8 pa[7];
#pragma unroll
        for (int kc = 0; kc < 7; ++kc) {
            const int ctA = 2*kc;
            const int ctB = (kc == 6) ? 12 : 2*kc + 1;
            unsigned A0 = (unsigned)__shfl((int)pk[ctA][0], src0);
            unsigned A1 = (unsigned)__shfl((int)pk[ctA][1], src0);
            unsigned A2 = (unsigned)__shfl((int)pk[ctA][0], src1);
            unsigned A3 = (unsigned)__shfl((int)pk[ctA][1], src1);
            unsigned B0 = (unsigned)__shfl((int)pk[ctB][0], src0);
            unsigned B1 = (unsigned)__shfl((int)pk[ctB][1], src0);
            unsigned B2 = (unsigned)__shfl((int)pk[ctB][0], src1);
            unsigned B3 = (unsigned)__shfl((int)pk[ctB][1], src1);
            bool hiHalf = (lq >= 2);
            union { unsigned u[4]; f16x8 v; } f;
            f.u[0] = hiHalf ? B0 : A0;
            f.u[1] = hiHalf ? B1 : A1;
            f.u[2] = hiHalf ? B2 : A2;
            f.u[3] = hiHalf ? B3 : A3;
            if (kc == 6 && hiHalf) { f.u[0]=0; f.u[1]=0; f.u[2]=0; f.u[3]=0; }
            pa[kc] = f.v;
        }

        f32x4 gacc[2];
#pragma unroll
        for (int ct = 0; ct < 2; ++ct) { gacc[ct][0]=0.f; gacc[ct][1]=0.f; gacc[ct][2]=0.f; gacc[ct][3]=0.f; }
        __builtin_amdgcn_s_setprio(1);
#pragma unroll
        for (int kc = 0; kc < 7; ++kc) {
#pragma unroll
            for (int ct = 0; ct < 2; ++ct) {
                f16x8 gf = *(f16x8*)&Gt[(ct*16 + lr)*SGT + kc*32 + lq*8];
                gacc[ct] = __builtin_amdgcn_mfma_f32_16x16x32_f16(pa[kc], gf, gacc[ct], 0, 0, 0);
            }
        }
        __builtin_amdgcn_s_setprio(0);

#pragma unroll
        for (int z = 0; z < 2; ++z) {
            int zi = z*64 + l;
            int zr = zi >> 3, zc = (zi & 7) << 3;
            f16x8 zz;
#pragma unroll
            for (int e = 0; e < 8; ++e) zz[e] = (f16)0.f;
            *(f16x8*)&wsh[zr*SWS + zc] = zz;
        }
        wfence();
#pragma unroll
        for (int rg = 0; rg < 4; ++rg) {
            int il = lq*4 + rg;
            int is_ = i0 + il;
            if (lr < 14 && is_ > 0) {
                unsigned v = div14((unsigned)(is_-1));
                int id2 = (int)v, ih2 = (is_-1) - (int)v*14;
                wsh[il*SWS + (lr - id2 + 15)]      = (f16)gacc[0][rg];
                wsh[il*SWS + 30 + (lr - ih2 + 15)] = (f16)gacc[1][rg];
            }
        }
        if (lq == 0 && !(i0 == 0 && lr == 0)) {
            wsh[lr*SWS + 0]  = (f16)pn00;
            wsh[lr*SWS + 30] = (f16)pn00;
        }
        if (i0 == 0) {
            float sv = (lq == 0) ? gacc[0][0] : 0.f;
            float sh = (lq == 0) ? gacc[1][0] : 0.f;
            sv += __shfl_xor(sv, 1); sv += __shfl_xor(sv, 2);
            sv += __shfl_xor(sv, 4); sv += __shfl_xor(sv, 8);
            sh += __shfl_xor(sh, 1); sh += __shfl_xor(sh, 2);
            sh += __shfl_xor(sh, 4); sh += __shfl_xor(sh, 8);
            if (l == 0) {
                wsh[0]  = (f16)(sv + pn00);
                wsh[30] = (f16)(sh + pn00);
            }
        }
        wfence();

        f16x8 sfr[2];
#pragma unroll
        for (int kc2 = 0; kc2 < 2; ++kc2)
            sfr[kc2] = *(f16x8*)&wsh[lr*SWS + kc2*32 + lq*8];

        f32x4 oacc[4];
#pragma unroll
        for (int ct = 0; ct < 4; ++ct) { oacc[ct][0]=0.f; oacc[ct][1]=0.f; oacc[ct][2]=0.f; oacc[ct][3]=0.f; }
        __builtin_amdgcn_s_setprio(1);
        const int swz = (lr & 7) << 3;
#pragma unroll
        for (int kc = 0; kc < 7; ++kc) {
#pragma unroll
            for (int ct = 0; ct < 4; ++ct) {
                f16x8 vf = *(f16x8*)&Vt[(ct*16 + lr)*SVT + ((kc*32 + lq*8) ^ swz)];
                oacc[ct] = __builtin_amdgcn_mfma_f32_16x16x32_f16(pa[kc], vf, oacc[ct], 0, 0, 0);
            }
        }
#pragma unroll
        for (int kc2 = 0; kc2 < 2; ++kc2) {
#pragma unroll
            for (int ct = 0; ct < 4; ++ct) {
                f16x8 vf = *(f16x8*)&Vt[(ct*16 + lr)*SVT + ((208 + kc2*32 + lq*8) ^ swz)];
                oacc[ct] = __builtin_amdgcn_mfma_f32_16x16x32_f16(sfr[kc2], vf, oacc[ct], 0, 0, 0);
            }
        }
        __builtin_amdgcn_s_setprio(0);

#pragma unroll
        for (int ct = 0; ct < 4; ++ct)
#pragma unroll
            for (int rg = 0; rg < 4; ++rg) {
                int io = i0 + lq*4 + rg;
                if (io < NTOK) {
                    int d = ct*16 + lr;
                    o_ws[((size_t)(b * NTOK + io) * NH + h) * HDIM + d] = (f16)oacc[ct][rg];
                }
            }
    }
}

extern "C" void kernel_launch(void* const* d_in, const int* in_sizes, int n_in,
                              void* d_out, int out_size, void* d_ws, size_t ws_size,
                              hipStream_t stream)
{
    const float* x     = (const float*)d_in[0];
    const float* wq    = (const float*)d_in[1];
    const float* wk    = (const float*)d_in[2];
    const float* wv    = (const float*)d_in[3];
    const float* wproj = (const float*)d_in[4];
    const float* bproj = (const float*)d_in[5];
    const float* rkv   = (const float*)d_in[6];
    const float* rkh   = (const float*)d_in[7];
    const float* rvv   = (const float*)d_in[8];
    const float* rvh   = (const float*)d_in[9];

    f16* ws = (f16*)d_ws;
    const size_t sz = (size_t)MROWS * EDIM;
    f16* xh    = ws;
    f16* qh    = xh + sz;
    f16* kh    = qh + sz;
    f16* vh    = kh + sz;
    f16* oh    = vh + sz;
    f16* wqkvT = oh + sz;
    f16* wpT   = wqkvT + (size_t)3*EDIM*EDIM;

    convert_x  <<<4728, 256, 0, stream>>>(x, xh);
    transpose_w<<<dim3(12, 12, 4), 256, 0, stream>>>(wq, wk, wv, wproj, wqkvT, wpT);
    gemm_h     <<<99*18, 256, 0, stream>>>(xh, wqkvT, qh, kh, vh,
                                           nullptr, nullptr, 0, 18);
    attn_mfma  <<<NB * NH, 768, 0, stream>>>(qh, kh, vh,
                                             rkv, rkh, rvv, rvh, oh);
    gemm_h     <<<99*6, 256, 0, stream>>>(oh, wpT, nullptr, nullptr, nullptr,
                                          (float*)d_out, bproj, 1, 6);
}

// Round 8
// 157.267 us; speedup vs baseline: 1.1587x; 1.1587x over previous
//
#include <hip/hip_runtime.h>
#include <math.h>

typedef _Float16 f16;
typedef __attribute__((ext_vector_type(8))) _Float16 f16x8;
typedef __attribute__((ext_vector_type(4))) _Float16 f16x4;
typedef __attribute__((ext_vector_type(4))) float f32x4;

#define NH 12
#define HDIM 64
#define NTOK 197
#define EDIM 768
#define NB 64
#define MROWS (NB*NTOK)   // 12608

__device__ __forceinline__ void wfence() {
    asm volatile("s_waitcnt lgkmcnt(0)" ::: "memory");
    __builtin_amdgcn_sched_barrier(0);
    __builtin_amdgcn_wave_barrier();
}

__device__ __forceinline__ unsigned div14(unsigned n) { return (n * 4682u) >> 16; }  // exact n<=206

__device__ __forceinline__ void gload16(const f16* g, f16* lds_base) {
    __builtin_amdgcn_global_load_lds(
        (const __attribute__((address_space(1))) void*)g,
        (__attribute__((address_space(3))) void*)lds_base, 16, 0, 0);
}

// ---------------------------------------------------------------------------
// x [12608x768] f32 -> f16.
// ---------------------------------------------------------------------------
__global__ __launch_bounds__(256) void convert_x(
    const float* __restrict__ x, f16* __restrict__ xh)
{
    int idx = blockIdx.x * 256 + threadIdx.x;
    const float4* s = (const float4*)x + (size_t)idx * 2;
    float4 a = s[0], b = s[1];
    f16x8 h;
    h[0]=(f16)a.x; h[1]=(f16)a.y; h[2]=(f16)a.z; h[3]=(f16)a.w;
    h[4]=(f16)b.x; h[5]=(f16)b.y; h[6]=(f16)b.z; h[7]=(f16)b.w;
    *(f16x8*)(xh + (size_t)idx * 8) = h;
}

// ---------------------------------------------------------------------------
// LDS-tiled transpose + f16: wT[n][k] = (f16)w[k][n].
// ---------------------------------------------------------------------------
__global__ __launch_bounds__(256) void transpose_w(
    const float* __restrict__ wq, const float* __restrict__ wk,
    const float* __restrict__ wv, const float* __restrict__ wp,
    f16* __restrict__ wqkvT, f16* __restrict__ wpT)
{
    __shared__ float T[64][65];
    int m = blockIdx.z;
    const float* src = (m==0)?wq:(m==1)?wk:(m==2)?wv:wp;
    int k0 = blockIdx.x * 64, n0 = blockIdx.y * 64;
    int cidx = threadIdx.x & 63, r4 = threadIdx.x >> 6;
#pragma unroll
    for (int rr = 0; rr < 16; ++rr) {
        int kl = rr*4 + r4;
        T[kl][cidx] = src[(size_t)(k0+kl)*EDIM + n0 + cidx];
    }
    __syncthreads();
    f16* dst = (m < 3) ? (wqkvT + (size_t)m*EDIM*EDIM) : wpT;
#pragma unroll
    for (int rr = 0; rr < 16; ++rr) {
        int nl = rr*4 + r4;
        dst[(size_t)(n0+nl)*EDIM + k0 + cidx] = (f16)T[cidx][nl];
    }
}

// ---------------------------------------------------------------------------
// 256x256-tile f16 MFMA GEMM, 8 waves, double-buffered global_load_lds with
// counted-drain pipeline (T3+T4 minimum recipe): per K-tile, stage t+1 into
// the idle buffer, compute t, then vmcnt(0) (hidden under compute) + raw
// barrier. LDS 128KB = A dbuf 64KB + B dbuf 64KB. XOR-swizzle (T2) applied
// via pre-swizzled global source col + swizzled ds_read col (rule #21).
// mode 0: f16 scatter to q/k/v [B,H,N,HD] via per-wave LDS-bounce (128B rows)
// mode 1: f32 out + bias, direct stores (64B segments).
// ---------------------------------------------------------------------------
__global__ __launch_bounds__(512, 2) void gemm256(
    const f16* __restrict__ A, const f16* __restrict__ Bt,
    f16* __restrict__ q_o, f16* __restrict__ k_o, f16* __restrict__ v_o,
    float* __restrict__ p_o, const float* __restrict__ bias, int mode, int nxb)
{
    __shared__ f16 lds[4*16384];   // [0..32767] A dbuf, [32768..65535] B dbuf

    const int tid = threadIdx.x;
    const int l = tid & 63, w = tid >> 6;
    const int lr = l & 15, lq = l >> 4;
    const int wr = w >> 2, wc = w & 3;          // wave grid 2M x 4N, 128x64 out

    // ---- XCD-aware bijective swizzle (m204), m-band-major ----
    const int nwg = gridDim.x, orig = blockIdx.x;
    const int xcd = orig & 7, qc = nwg >> 3, rc = nwg & 7;
    const int wgid = (xcd < rc ? xcd*(qc+1) : rc*(qc+1) + (xcd-rc)*qc) + (orig >> 3);
    const int mband = wgid / nxb, nband = wgid - mband*nxb;
    const int m0 = mband << 8, n0 = nband << 8;

    // ---- staging: thread covers row p*64 + (tid>>3), src col pre-swizzled ----
    const int scol = (((tid & 7) ^ ((tid >> 3) & 7)) << 3);
    const f16* aG[4]; const f16* bG[4];
#pragma unroll
    for (int p = 0; p < 4; ++p) {
        int rt = p*64 + (tid >> 3);
        int ra = m0 + rt; if (ra >= MROWS) ra = MROWS - 1;
        aG[p] = A  + (size_t)ra * EDIM + scol;
        bG[p] = Bt + (size_t)(n0 + rt) * EDIM + scol;
    }
    const int lbase = w * 512;   // + p*4096 (+cur*16384); lane offset implicit

    f32x4 acc[8][4];
#pragma unroll
    for (int mt = 0; mt < 8; ++mt)
#pragma unroll
        for (int nt = 0; nt < 4; ++nt) {
            acc[mt][nt][0]=0.f; acc[mt][nt][1]=0.f;
            acc[mt][nt][2]=0.f; acc[mt][nt][3]=0.f;
        }

    // ---- prologue: stage K-tile 0 into buf0, drain, barrier ----
#pragma unroll
    for (int p = 0; p < 4; ++p) {
        gload16(aG[p], &lds[p*4096 + lbase]);
        gload16(bG[p], &lds[32768 + p*4096 + lbase]);
    }
    asm volatile("s_waitcnt vmcnt(0)" ::: "memory");
    __builtin_amdgcn_sched_barrier(0);
    __builtin_amdgcn_s_barrier();

    const int swz = (lr & 7) << 3;
    int cur = 0;
    for (int kt = 0; kt < 12; ++kt) {
        if (kt < 11) {                    // issue next K-tile into idle buffer
            const int ko = (kt + 1) * 64;
            const int nb = (cur ^ 1) * 16384;
#pragma unroll
            for (int p = 0; p < 4; ++p) {
                gload16(aG[p] + ko, &lds[nb + p*4096 + lbase]);
                gload16(bG[p] + ko, &lds[32768 + nb + p*4096 + lbase]);
            }
        }
        __builtin_amdgcn_sched_barrier(0);
        const f16* Ab = &lds[cur * 16384];
        const f16* Bb = &lds[32768 + cur * 16384];
#pragma unroll
        for (int ks = 0; ks < 2; ++ks) {
            const int kb = (ks*32 + lq*8) ^ swz;
            f16x8 bf[4];
#pragma unroll
            for (int nt = 0; nt < 4; ++nt)
                bf[nt] = *(const f16x8*)&Bb[(wc*64 + nt*16 + lr)*64 + kb];
#pragma unroll
            for (int mt = 0; mt < 8; ++mt) {
                f16x8 af = *(const f16x8*)&Ab[(wr*128 + mt*16 + lr)*64 + kb];
#pragma unroll
                for (int nt = 0; nt < 4; ++nt)
                    acc[mt][nt] = __builtin_amdgcn_mfma_f32_16x16x32_f16(
                        af, bf[nt], acc[mt][nt], 0, 0, 0);
            }
        }
        // next tile landed (latency hidden under the 64 MFMAs) + all waves done
        asm volatile("s_waitcnt vmcnt(0)" ::: "memory");
        __builtin_amdgcn_sched_barrier(0);
        __builtin_amdgcn_s_barrier();
        cur ^= 1;
    }

    if (mode == 0) {
        const int mat   = n0 / EDIM;                  // 768 % 256 == 0: no straddle
        const int hbase = ((n0 % EDIM) >> 6) + wc;
        f16* dst = (mat == 0) ? q_o : (mat == 1) ? k_o : v_o;
        f16* scr = &lds[w * 2304];                    // 32 rows x 72 f16, per-wave
#pragma unroll
        for (int mt2 = 0; mt2 < 4; ++mt2) {
#pragma unroll
            for (int mtp = 0; mtp < 2; ++mtp) {
                const int mt = mt2*2 + mtp;
#pragma unroll
                for (int nt = 0; nt < 4; ++nt)
#pragma unroll
                    for (int rg = 0; rg < 4; ++rg)
                        scr[(mtp*16 + lq*4 + rg)*72 + nt*16 + lr] = (f16)acc[mt][nt][rg];
            }
            wfence();
#pragma unroll
            for (int i = 0; i < 4; ++i) {
                int row = (l >> 3) + i*8;             // 0..31
                f16x8 v = *(const f16x8*)&scr[row*72 + (l & 7)*8];
                int R = m0 + wr*128 + mt2*32 + row;
                if (R < MROWS) {
                    int bb = R / NTOK, nn = R - bb*NTOK;
                    *(f16x8*)&dst[((size_t)(bb*NH + hbase)*NTOK + nn)*HDIM + (l & 7)*8] = v;
                }
            }
            wfence();
        }
    } else {
#pragma unroll
        for (int mt = 0; mt < 8; ++mt)
#pragma unroll
            for (int rg = 0; rg < 4; ++rg) {
                int R = m0 + wr*128 + mt*16 + lq*4 + rg;
                if (R < MROWS) {
                    float* base = p_o + (size_t)R * EDIM + n0 + wc*64;
#pragma unroll
                    for (int nt = 0; nt < 4; ++nt) {
                        int c = nt*16 + lr;
                        base[c] = acc[mt][nt][rg] + bias[n0 + wc*64 + c];
                    }
                }
            }
    }
}

// ---------------------------------------------------------------------------
// MFMA fused attention v3 (unchanged from round 6).
// ---------------------------------------------------------------------------
#define SKE 104
#define SVT 320
#define SGT 232
#define SWS 72

__global__ __launch_bounds__(768, 1) void attn_mfma(
    const f16* __restrict__ q_ws, const f16* __restrict__ k_ws,
    const f16* __restrict__ v_ws,
    const float* __restrict__ rkv, const float* __restrict__ rkh,
    const float* __restrict__ rvv, const float* __restrict__ rvh,
    f16* __restrict__ o_ws)
{
    __shared__ f16 Kle[272*SKE];
    __shared__ f16 Vt[64*SVT];
    __shared__ f16 Gt[32*SGT];
    __shared__ f16 WSh[12*16*SWS];

    const int tid = threadIdx.x;
    const int w = tid >> 6, l = tid & 63;
    const int lr = l & 15, lq = l >> 4;
    const int bh = blockIdx.x;
    const int b = bh / NH, h = bh - b * NH;
    const f16* Qp = q_ws + (size_t)bh * NTOK * HDIM;
    const f16* Kp = k_ws + (size_t)bh * NTOK * HDIM;
    const f16* Vp = v_ws + (size_t)bh * NTOK * HDIM;
    f16* wsh = &WSh[w * 16 * SWS];

    for (int idx = tid; idx < 272*13; idx += 768) {
        int row = idx / 13, c = idx - row*13;
        int c8 = c << 3;
        f16x8 hv;
#pragma unroll
        for (int e = 0; e < 8; ++e) hv[e] = (f16)0.f;
        if (c < 8) {
            if (row < NTOK) {
                hv = *(const f16x8*)(Kp + row*64 + c8);
            } else if (row >= 208 && row < 238) {
                const float* src = rkv + (row-208)*64 + c8;
                float4 a = *(const float4*)src, d = *(const float4*)(src+4);
                hv[0]=(f16)a.x; hv[1]=(f16)a.y; hv[2]=(f16)a.z; hv[3]=(f16)a.w;
                hv[4]=(f16)d.x; hv[5]=(f16)d.y; hv[6]=(f16)d.z; hv[7]=(f16)d.w;
            } else if (row >= 240 && row < 270) {
                const float* src = rkh + (row-240)*64 + c8;
                float4 a = *(const float4*)src, d = *(const float4*)(src+4);
                hv[0]=(f16)a.x; hv[1]=(f16)a.y; hv[2]=(f16)a.z; hv[3]=(f16)a.w;
                hv[4]=(f16)d.x; hv[5]=(f16)d.y; hv[6]=(f16)d.z; hv[7]=(f16)d.w;
            }
        } else if (c < 12 && row < 208) {
            int gbase = (c - 8) << 3;
            if (row == 0) {
#pragma unroll
                for (int e = 0; e < 8; ++e) {
                    int g = gbase + e;
                    hv[e] = (g == 14 || g == 30) ? (f16)1.f : (f16)0.f;
                }
            } else if (row <= 196) {
                int rm = row - 1;
                int gv = (int)div14((unsigned)rm);
                int gh = rm - gv*14;
#pragma unroll
                for (int e = 0; e < 8; ++e) {
                    int g = gbase + e;
                    hv[e] = (g == gv || g == 16 + gh) ? (f16)1.f : (f16)0.f;
                }
            }
        }
        *(f16x8*)&Kle[row*SKE + c8] = hv;
    }

    for (int idx = tid; idx < 8*SVT; idx += 768) {
        int dlow = idx & 7, k = idx >> 3;
        int kx = k ^ (dlow << 3);
        bool isV = (k < NTOK), isA = (k >= 208 && k < 238), isB = (k >= 238 && k < 268);
#pragma unroll
        for (int e = 0; e < 8; ++e) {
            int d = (e << 3) + dlow;
            f16 val = (f16)0.f;
            if (isV)      val = Vp[k*64 + d];
            else if (isA) val = (f16)rvv[(k-208)*64 + d];
            else if (isB) val = (f16)rvh[(k-238)*64 + d];
            Vt[d*SVT + kx] = val;
        }
    }

    for (int idx = tid; idx < 32*29; idx += 768) {
        int g = idx / 29, c = idx - g*29, c8 = c << 3;
        f16x8 hv;
#pragma unroll
        for (int e = 0; e < 8; ++e) hv[e] = (f16)0.f;
        if (g < 14 || (g >= 16 && g < 30)) {
#pragma unroll
            for (int e = 0; e < 8; ++e) {
                int j = c8 + e;
                if (j >= 1 && j <= 196) {
                    int jm = j - 1;
                    int gv = (int)div14((unsigned)jm);
                    int gh = jm - gv*14;
                    if ((g < 14 && gv == g) || (g >= 16 && gh == g - 16))
                        hv[e] = (f16)1.f;
                }
            }
        }
        *(f16x8*)&Gt[g*SGT + c8] = hv;
    }
    __syncthreads();

    const int src0 = ((l >> 4) & 1) * 32 + lr;
    const int src1 = src0 + 16;

    for (int tt = w; tt < 13; tt += 12) {
        const int i0 = tt * 16;
        const int iq = i0 + lr;
        const int iqc = (iq > 196) ? 196 : iq;
        const f16* qsrc = Qp + iqc*64 + lq*8;
        f16x8 qf0 = *(const f16x8*)qsrc;
        f16x8 qf1 = *(const f16x8*)(qsrc + 32);

        __builtin_amdgcn_s_setprio(1);
        f32x4 pacc[4];
#pragma unroll
        for (int ct = 0; ct < 4; ++ct) {
            f32x4 a; a[0]=0.f; a[1]=0.f; a[2]=0.f; a[3]=0.f;
            const int krow = (13+ct)*16 + lr;
            f16x8 kf0 = *(f16x8*)&Kle[krow*SKE + lq*8];
            f16x8 kf1 = *(f16x8*)&Kle[krow*SKE + 32 + lq*8];
            a = __builtin_amdgcn_mfma_f32_16x16x32_f16(kf0, qf0, a, 0, 0, 0);
            a = __builtin_amdgcn_mfma_f32_16x16x32_f16(kf1, qf1, a, 0, 0, 0);
            pacc[ct] = a;
        }
        __builtin_amdgcn_s_setprio(0);
#pragma unroll
        for (int ct = 0; ct < 4; ++ct)
#pragma unroll
            for (int rg = 0; rg < 4; ++rg)
                wsh[lr*SWS + ct*16 + lq*4 + rg] = (f16)pacc[ct][rg];
        wfence();

        int id_ = 0, ih_ = 0;
        const bool qcls = (iq == 0);
        if (iq > 0) { unsigned v = div14((unsigned)(iq-1)); id_ = (int)v; ih_ = (iq-1) - (int)v*14; }
        f16x8 qcf;
#pragma unroll
        for (int e = 0; e < 8; ++e) {
            int g = lq*8 + e;
            int toff;
            if (g < 14)       toff = qcls ? 0 : (g - id_ + 15);
            else if (g == 14) toff = 0;
            else if (g == 15) toff = 63;
            else if (g < 30)  toff = qcls ? 32 : (32 + (g-16) - ih_ + 15);
            else if (g == 30) toff = 32;
            else              toff = 63;
            qcf[e] = wsh[lr*SWS + toff];
        }

        f32x4 acc[13];
        __builtin_amdgcn_s_setprio(1);
#pragma unroll
        for (int ct = 0; ct < 13; ++ct) {
            f32x4 a; a[0]=0.f; a[1]=0.f; a[2]=0.f; a[3]=0.f;
            const int krow = ct*16 + lr;
            f16x8 kf0 = *(f16x8*)&Kle[krow*SKE + lq*8];
            f16x8 kf1 = *(f16x8*)&Kle[krow*SKE + 32 + lq*8];
            f16x8 gf  = *(f16x8*)&Kle[krow*SKE + 64 + lq*8];
            a = __builtin_amdgcn_mfma_f32_16x16x32_f16(kf0, qf0, a, 0, 0, 0);
            a = __builtin_amdgcn_mfma_f32_16x16x32_f16(kf1, qf1, a, 0, 0, 0);
            a = __builtin_amdgcn_mfma_f32_16x16x32_f16(gf,  qcf, a, 0, 0, 0);
            acc[ct] = a;
        }
        __builtin_amdgcn_s_setprio(0);

#pragma unroll
        for (int rg = 0; rg < 4; ++rg)
            if (lq*4 + rg > 4) acc[12][rg] = -1e30f;

        float m = -1e30f;
#pragma unroll
        for (int ct = 0; ct < 13; ++ct)
#pragma unroll
            for (int rg = 0; rg < 4; ++rg) m = fmaxf(m, acc[ct][rg]);
        m = fmaxf(m, __shfl_xor(m, 16));
        m = fmaxf(m, __shfl_xor(m, 32));
        const float C1 = 0.125f * 1.44269504088896f;
        const float nm = -m * C1;
        float ssum = 0.f;
#pragma unroll
        for (int ct = 0; ct < 13; ++ct)
#pragma unroll
            for (int rg = 0; rg < 4; ++rg) {
                float p = exp2f(fmaf(acc[ct][rg], C1, nm));
                acc[ct][rg] = p; ssum += p;
            }
        ssum += __shfl_xor(ssum, 16);
        ssum += __shfl_xor(ssum, 32);
        const float inv = 1.f / ssum;
        const float pn00 = acc[0][0] * inv;

        unsigned pk[13][2];
#pragma unroll
        for (int ct = 0; ct < 13; ++ct) {
            union { f16x4 hh; unsigned u[2]; } t;
            t.hh[0] = (f16)(acc[ct][0] * inv);
            t.hh[1] = (f16)(acc[ct][1] * inv);
            t.hh[2] = (f16)(acc[ct][2] * inv);
            t.hh[3] = (f16)(acc[ct][3] * inv);
            pk[ct][0] = t.u[0]; pk[ct][1] = t.u[1];
        }

        f16x8 pa[7];
#pragma unroll
        for (int kc = 0; kc < 7; ++kc) {
            const int ctA = 2*kc;
            const int ctB = (kc == 6) ? 12 : 2*kc + 1;
            unsigned A0 = (unsigned)__shfl((int)pk[ctA][0], src0);
            unsigned A1 = (unsigned)__shfl((int)pk[ctA][1], src0);
            unsigned A2 = (unsigned)__shfl((int)pk[ctA][0], src1);
            unsigned A3 = (unsigned)__shfl((int)pk[ctA][1], src1);
            unsigned B0 = (unsigned)__shfl((int)pk[ctB][0], src0);
            unsigned B1 = (unsigned)__shfl((int)pk[ctB][1], src0);
            unsigned B2 = (unsigned)__shfl((int)pk[ctB][0], src1);
            unsigned B3 = (unsigned)__shfl((int)pk[ctB][1], src1);
            bool hiHalf = (lq >= 2);
            union { unsigned u[4]; f16x8 v; } f;
            f.u[0] = hiHalf ? B0 : A0;
            f.u[1] = hiHalf ? B1 : A1;
            f.u[2] = hiHalf ? B2 : A2;
            f.u[3] = hiHalf ? B3 : A3;
            if (kc == 6 && hiHalf) { f.u[0]=0; f.u[1]=0; f.u[2]=0; f.u[3]=0; }
            pa[kc] = f.v;
        }

        f32x4 gacc[2];
#pragma unroll
        for (int ct = 0; ct < 2; ++ct) { gacc[ct][0]=0.f; gacc[ct][1]=0.f; gacc[ct][2]=0.f; gacc[ct][3]=0.f; }
        __builtin_amdgcn_s_setprio(1);
#pragma unroll
        for (int kc = 0; kc < 7; ++kc) {
#pragma unroll
            for (int ct = 0; ct < 2; ++ct) {
                f16x8 gf = *(f16x8*)&Gt[(ct*16 + lr)*SGT + kc*32 + lq*8];
                gacc[ct] = __builtin_amdgcn_mfma_f32_16x16x32_f16(pa[kc], gf, gacc[ct], 0, 0, 0);
            }
        }
        __builtin_amdgcn_s_setprio(0);

#pragma unroll
        for (int z = 0; z < 2; ++z) {
            int zi = z*64 + l;
            int zr = zi >> 3, zc = (zi & 7) << 3;
            f16x8 zz;
#pragma unroll
            for (int e = 0; e < 8; ++e) zz[e] = (f16)0.f;
            *(f16x8*)&wsh[zr*SWS + zc] = zz;
        }
        wfence();
#pragma unroll
        for (int rg = 0; rg < 4; ++rg) {
            int il = lq*4 + rg;
            int is_ = i0 + il;
            if (lr < 14 && is_ > 0) {
                unsigned v = div14((unsigned)(is_-1));
                int id2 = (int)v, ih2 = (is_-1) - (int)v*14;
                wsh[il*SWS + (lr - id2 + 15)]      = (f16)gacc[0][rg];
                wsh[il*SWS + 30 + (lr - ih2 + 15)] = (f16)gacc[1][rg];
            }
        }
        if (lq == 0 && !(i0 == 0 && lr == 0)) {
            wsh[lr*SWS + 0]  = (f16)pn00;
            wsh[lr*SWS + 30] = (f16)pn00;
        }
        if (i0 == 0) {
            float sv = (lq == 0) ? gacc[0][0] : 0.f;
            float sh = (lq == 0) ? gacc[1][0] : 0.f;
            sv += __shfl_xor(sv, 1); sv += __shfl_xor(sv, 2);
            sv += __shfl_xor(sv, 4); sv += __shfl_xor(sv, 8);
            sh += __shfl_xor(sh, 1); sh += __shfl_xor(sh, 2);
            sh += __shfl_xor(sh, 4); sh += __shfl_xor(sh, 8);
            if (l == 0) {
                wsh[0]  = (f16)(sv + pn00);
                wsh[30] = (f16)(sh + pn00);
            }
        }
        wfence();

        f16x8 sfr[2];
#pragma unroll
        for (int kc2 = 0; kc2 < 2; ++kc2)
            sfr[kc2] = *(f16x8*)&wsh[lr*SWS + kc2*32 + lq*8];

        f32x4 oacc[4];
#pragma unroll
        for (int ct = 0; ct < 4; ++ct) { oacc[ct][0]=0.f; oacc[ct][1]=0.f; oacc[ct][2]=0.f; oacc[ct][3]=0.f; }
        __builtin_amdgcn_s_setprio(1);
        const int swz = (lr & 7) << 3;
#pragma unroll
        for (int kc = 0; kc < 7; ++kc) {
#pragma unroll
            for (int ct = 0; ct < 4; ++ct) {
                f16x8 vf = *(f16x8*)&Vt[(ct*16 + lr)*SVT + ((kc*32 + lq*8) ^ swz)];
                oacc[ct] = __builtin_amdgcn_mfma_f32_16x16x32_f16(pa[kc], vf, oacc[ct], 0, 0, 0);
            }
        }
#pragma unroll
        for (int kc2 = 0; kc2 < 2; ++kc2) {
#pragma unroll
            for (int ct = 0; ct < 4; ++ct) {
                f16x8 vf = *(f16x8*)&Vt[(ct*16 + lr)*SVT + ((208 + kc2*32 + lq*8) ^ swz)];
                oacc[ct] = __builtin_amdgcn_mfma_f32_16x16x32_f16(sfr[kc2], vf, oacc[ct], 0, 0, 0);
            }
        }
        __builtin_amdgcn_s_setprio(0);

#pragma unroll
        for (int ct = 0; ct < 4; ++ct)
#pragma unroll
            for (int rg = 0; rg < 4; ++rg) {
                int io = i0 + lq*4 + rg;
                if (io < NTOK) {
                    int d = ct*16 + lr;
                    o_ws[((size_t)(b * NTOK + io) * NH + h) * HDIM + d] = (f16)oacc[ct][rg];
                }
            }
    }
}

extern "C" void kernel_launch(void* const* d_in, const int* in_sizes, int n_in,
                              void* d_out, int out_size, void* d_ws, size_t ws_size,
                              hipStream_t stream)
{
    const float* x     = (const float*)d_in[0];
    const float* wq    = (const float*)d_in[1];
    const float* wk    = (const float*)d_in[2];
    const float* wv    = (const float*)d_in[3];
    const float* wproj = (const float*)d_in[4];
    const float* bproj = (const float*)d_in[5];
    const float* rkv   = (const float*)d_in[6];
    const float* rkh   = (const float*)d_in[7];
    const float* rvv   = (const float*)d_in[8];
    const float* rvh   = (const float*)d_in[9];

    f16* ws = (f16*)d_ws;
    const size_t sz = (size_t)MROWS * EDIM;
    f16* xh    = ws;
    f16* qh    = xh + sz;
    f16* kh    = qh + sz;
    f16* vh    = kh + sz;
    f16* oh    = vh + sz;
    f16* wqkvT = oh + sz;
    f16* wpT   = wqkvT + (size_t)3*EDIM*EDIM;

    convert_x  <<<4728, 256, 0, stream>>>(x, xh);
    transpose_w<<<dim3(12, 12, 4), 256, 0, stream>>>(wq, wk, wv, wproj, wqkvT, wpT);
    gemm256    <<<50*9, 512, 0, stream>>>(xh, wqkvT, qh, kh, vh,
                                          nullptr, nullptr, 0, 9);
    attn_mfma  <<<NB * NH, 768, 0, stream>>>(qh, kh, vh,
                                             rkv, rkh, rvv, rvh, oh);
    gemm256    <<<50*3, 512, 0, stream>>>(oh, wpT, nullptr, nullptr, nullptr,
                                          (float*)d_out, bproj, 1, 3);
}

// Round 9
// 154.217 us; speedup vs baseline: 1.1816x; 1.0198x over previous
//
#include <hip/hip_runtime.h>
#include <math.h>

typedef _Float16 f16;
typedef __attribute__((ext_vector_type(8))) _Float16 f16x8;
typedef __attribute__((ext_vector_type(4))) _Float16 f16x4;
typedef __attribute__((ext_vector_type(4))) float f32x4;

#define NH 12
#define HDIM 64
#define NTOK 197
#define EDIM 768
#define NB 64
#define MROWS (NB*NTOK)   // 12608

__device__ __forceinline__ void wfence() {
    asm volatile("s_waitcnt lgkmcnt(0)" ::: "memory");
    __builtin_amdgcn_sched_barrier(0);
    __builtin_amdgcn_wave_barrier();
}

__device__ __forceinline__ unsigned div14(unsigned n) { return (n * 4682u) >> 16; }  // exact n<=206

__device__ __forceinline__ void gload16(const f16* g, f16* lds_base) {
    __builtin_amdgcn_global_load_lds(
        (const __attribute__((address_space(1))) void*)g,
        (__attribute__((address_space(3))) void*)lds_base, 16, 0, 0);
}

// ---------------------------------------------------------------------------
// x [12608x768] f32 -> f16.  (HBM-bound, ~6.4 TB/s — at roofline.)
// ---------------------------------------------------------------------------
__global__ __launch_bounds__(256) void convert_x(
    const float* __restrict__ x, f16* __restrict__ xh)
{
    int idx = blockIdx.x * 256 + threadIdx.x;
    const float4* s = (const float4*)x + (size_t)idx * 2;
    float4 a = s[0], b = s[1];
    f16x8 h;
    h[0]=(f16)a.x; h[1]=(f16)a.y; h[2]=(f16)a.z; h[3]=(f16)a.w;
    h[4]=(f16)b.x; h[5]=(f16)b.y; h[6]=(f16)b.z; h[7]=(f16)b.w;
    *(f16x8*)(xh + (size_t)idx * 8) = h;
}

// ---------------------------------------------------------------------------
// LDS-tiled transpose + f16: wT[n][k] = (f16)w[k][n].
// ---------------------------------------------------------------------------
__global__ __launch_bounds__(256) void transpose_w(
    const float* __restrict__ wq, const float* __restrict__ wk,
    const float* __restrict__ wv, const float* __restrict__ wp,
    f16* __restrict__ wqkvT, f16* __restrict__ wpT)
{
    __shared__ float T[64][65];
    int m = blockIdx.z;
    const float* src = (m==0)?wq:(m==1)?wk:(m==2)?wv:wp;
    int k0 = blockIdx.x * 64, n0 = blockIdx.y * 64;
    int cidx = threadIdx.x & 63, r4 = threadIdx.x >> 6;
#pragma unroll
    for (int rr = 0; rr < 16; ++rr) {
        int kl = rr*4 + r4;
        T[kl][cidx] = src[(size_t)(k0+kl)*EDIM + n0 + cidx];
    }
    __syncthreads();
    f16* dst = (m < 3) ? (wqkvT + (size_t)m*EDIM*EDIM) : wpT;
#pragma unroll
    for (int rr = 0; rr < 16; ++rr) {
        int nl = rr*4 + r4;
        dst[(size_t)(n0+nl)*EDIM + k0 + cidx] = (f16)T[cidx][nl];
    }
}

// ---------------------------------------------------------------------------
// 256x256-tile f16 MFMA GEMM, 8 waves, dbuf global_load_lds + counted-drain
// pipeline (unchanged from round 8).
// ---------------------------------------------------------------------------
__global__ __launch_bounds__(512, 2) void gemm256(
    const f16* __restrict__ A, const f16* __restrict__ Bt,
    f16* __restrict__ q_o, f16* __restrict__ k_o, f16* __restrict__ v_o,
    float* __restrict__ p_o, const float* __restrict__ bias, int mode, int nxb)
{
    __shared__ f16 lds[4*16384];

    const int tid = threadIdx.x;
    const int l = tid & 63, w = tid >> 6;
    const int lr = l & 15, lq = l >> 4;
    const int wr = w >> 2, wc = w & 3;

    const int nwg = gridDim.x, orig = blockIdx.x;
    const int xcd = orig & 7, qc = nwg >> 3, rc = nwg & 7;
    const int wgid = (xcd < rc ? xcd*(qc+1) : rc*(qc+1) + (xcd-rc)*qc) + (orig >> 3);
    const int mband = wgid / nxb, nband = wgid - mband*nxb;
    const int m0 = mband << 8, n0 = nband << 8;

    const int scol = (((tid & 7) ^ ((tid >> 3) & 7)) << 3);
    const f16* aG[4]; const f16* bG[4];
#pragma unroll
    for (int p = 0; p < 4; ++p) {
        int rt = p*64 + (tid >> 3);
        int ra = m0 + rt; if (ra >= MROWS) ra = MROWS - 1;
        aG[p] = A  + (size_t)ra * EDIM + scol;
        bG[p] = Bt + (size_t)(n0 + rt) * EDIM + scol;
    }
    const int lbase = w * 512;

    f32x4 acc[8][4];
#pragma unroll
    for (int mt = 0; mt < 8; ++mt)
#pragma unroll
        for (int nt = 0; nt < 4; ++nt) {
            acc[mt][nt][0]=0.f; acc[mt][nt][1]=0.f;
            acc[mt][nt][2]=0.f; acc[mt][nt][3]=0.f;
        }

#pragma unroll
    for (int p = 0; p < 4; ++p) {
        gload16(aG[p], &lds[p*4096 + lbase]);
        gload16(bG[p], &lds[32768 + p*4096 + lbase]);
    }
    asm volatile("s_waitcnt vmcnt(0)" ::: "memory");
    __builtin_amdgcn_sched_barrier(0);
    __builtin_amdgcn_s_barrier();

    const int swz = (lr & 7) << 3;
    int cur = 0;
    for (int kt = 0; kt < 12; ++kt) {
        if (kt < 11) {
            const int ko = (kt + 1) * 64;
            const int nb = (cur ^ 1) * 16384;
#pragma unroll
            for (int p = 0; p < 4; ++p) {
                gload16(aG[p] + ko, &lds[nb + p*4096 + lbase]);
                gload16(bG[p] + ko, &lds[32768 + nb + p*4096 + lbase]);
            }
        }
        __builtin_amdgcn_sched_barrier(0);
        const f16* Ab = &lds[cur * 16384];
        const f16* Bb = &lds[32768 + cur * 16384];
#pragma unroll
        for (int ks = 0; ks < 2; ++ks) {
            const int kb = (ks*32 + lq*8) ^ swz;
            f16x8 bf[4];
#pragma unroll
            for (int nt = 0; nt < 4; ++nt)
                bf[nt] = *(const f16x8*)&Bb[(wc*64 + nt*16 + lr)*64 + kb];
#pragma unroll
            for (int mt = 0; mt < 8; ++mt) {
                f16x8 af = *(const f16x8*)&Ab[(wr*128 + mt*16 + lr)*64 + kb];
#pragma unroll
                for (int nt = 0; nt < 4; ++nt)
                    acc[mt][nt] = __builtin_amdgcn_mfma_f32_16x16x32_f16(
                        af, bf[nt], acc[mt][nt], 0, 0, 0);
            }
        }
        asm volatile("s_waitcnt vmcnt(0)" ::: "memory");
        __builtin_amdgcn_sched_barrier(0);
        __builtin_amdgcn_s_barrier();
        cur ^= 1;
    }

    if (mode == 0) {
        const int mat   = n0 / EDIM;
        const int hbase = ((n0 % EDIM) >> 6) + wc;
        f16* dst = (mat == 0) ? q_o : (mat == 1) ? k_o : v_o;
        f16* scr = &lds[w * 2304];
#pragma unroll
        for (int mt2 = 0; mt2 < 4; ++mt2) {
#pragma unroll
            for (int mtp = 0; mtp < 2; ++mtp) {
                const int mt = mt2*2 + mtp;
#pragma unroll
                for (int nt = 0; nt < 4; ++nt)
#pragma unroll
                    for (int rg = 0; rg < 4; ++rg)
                        scr[(mtp*16 + lq*4 + rg)*72 + nt*16 + lr] = (f16)acc[mt][nt][rg];
            }
            wfence();
#pragma unroll
            for (int i = 0; i < 4; ++i) {
                int row = (l >> 3) + i*8;
                f16x8 v = *(const f16x8*)&scr[row*72 + (l & 7)*8];
                int R = m0 + wr*128 + mt2*32 + row;
                if (R < MROWS) {
                    int bb = R / NTOK, nn = R - bb*NTOK;
                    *(f16x8*)&dst[((size_t)(bb*NH + hbase)*NTOK + nn)*HDIM + (l & 7)*8] = v;
                }
            }
            wfence();
        }
    } else {
#pragma unroll
        for (int mt = 0; mt < 8; ++mt)
#pragma unroll
            for (int rg = 0; rg < 4; ++rg) {
                int R = m0 + wr*128 + mt*16 + lq*4 + rg;
                if (R < MROWS) {
                    float* base = p_o + (size_t)R * EDIM + n0 + wc*64;
#pragma unroll
                    for (int nt = 0; nt < 4; ++nt) {
                        int c = nt*16 + lr;
                        base[c] = acc[mt][nt][rg] + bias[n0 + wc*64 + c];
                    }
                }
            }
    }
}

// ---------------------------------------------------------------------------
// MFMA fused attention v4: 13 waves (832 thr), exactly ONE 16-query tile per
// wave (208 rows = 13x16) — removes the wave-0 double-tile serial tail that
// capped round 8 at 2x single-tile block time. Logic otherwise = round 6/8.
// ---------------------------------------------------------------------------
#define SKE 104
#define SVT 320
#define SGT 232
#define SWS 72
#define ATHR 832

__global__ __launch_bounds__(ATHR, 1) void attn_mfma(
    const f16* __restrict__ q_ws, const f16* __restrict__ k_ws,
    const f16* __restrict__ v_ws,
    const float* __restrict__ rkv, const float* __restrict__ rkh,
    const float* __restrict__ rvv, const float* __restrict__ rvh,
    f16* __restrict__ o_ws)
{
    __shared__ f16 Kle[272*SKE];     // 56576 B
    __shared__ f16 Vt[64*SVT];       // 40960 B
    __shared__ f16 Gt[32*SGT];       // 14848 B
    __shared__ f16 WSh[13*16*SWS];   // 29952 B  (total 142336 B)

    const int tid = threadIdx.x;
    const int w = tid >> 6, l = tid & 63;
    const int lr = l & 15, lq = l >> 4;
    const int bh = blockIdx.x;
    const int b = bh / NH, h = bh - b * NH;
    const f16* Qp = q_ws + (size_t)bh * NTOK * HDIM;
    const f16* Kp = k_ws + (size_t)bh * NTOK * HDIM;
    const f16* Vp = v_ws + (size_t)bh * NTOK * HDIM;
    f16* wsh = &WSh[w * 16 * SWS];

    for (int idx = tid; idx < 272*13; idx += ATHR) {
        int row = idx / 13, c = idx - row*13;
        int c8 = c << 3;
        f16x8 hv;
#pragma unroll
        for (int e = 0; e < 8; ++e) hv[e] = (f16)0.f;
        if (c < 8) {
            if (row < NTOK) {
                hv = *(const f16x8*)(Kp + row*64 + c8);
            } else if (row >= 208 && row < 238) {
                const float* src = rkv + (row-208)*64 + c8;
                float4 a = *(const float4*)src, d = *(const float4*)(src+4);
                hv[0]=(f16)a.x; hv[1]=(f16)a.y; hv[2]=(f16)a.z; hv[3]=(f16)a.w;
                hv[4]=(f16)d.x; hv[5]=(f16)d.y; hv[6]=(f16)d.z; hv[7]=(f16)d.w;
            } else if (row >= 240 && row < 270) {
                const float* src = rkh + (row-240)*64 + c8;
                float4 a = *(const float4*)src, d = *(const float4*)(src+4);
                hv[0]=(f16)a.x; hv[1]=(f16)a.y; hv[2]=(f16)a.z; hv[3]=(f16)a.w;
                hv[4]=(f16)d.x; hv[5]=(f16)d.y; hv[6]=(f16)d.z; hv[7]=(f16)d.w;
            }
        } else if (c < 12 && row < 208) {
            int gbase = (c - 8) << 3;
            if (row == 0) {
#pragma unroll
                for (int e = 0; e < 8; ++e) {
                    int g = gbase + e;
                    hv[e] = (g == 14 || g == 30) ? (f16)1.f : (f16)0.f;
                }
            } else if (row <= 196) {
                int rm = row - 1;
                int gv = (int)div14((unsigned)rm);
                int gh = rm - gv*14;
#pragma unroll
                for (int e = 0; e < 8; ++e) {
                    int g = gbase + e;
                    hv[e] = (g == gv || g == 16 + gh) ? (f16)1.f : (f16)0.f;
                }
            }
        }
        *(f16x8*)&Kle[row*SKE + c8] = hv;
    }

    for (int idx = tid; idx < 8*SVT; idx += ATHR) {
        int dlow = idx & 7, k = idx >> 3;
        int kx = k ^ (dlow << 3);
        bool isV = (k < NTOK), isA = (k >= 208 && k < 238), isB = (k >= 238 && k < 268);
#pragma unroll
        for (int e = 0; e < 8; ++e) {
            int d = (e << 3) + dlow;
            f16 val = (f16)0.f;
            if (isV)      val = Vp[k*64 + d];
            else if (isA) val = (f16)rvv[(k-208)*64 + d];
            else if (isB) val = (f16)rvh[(k-238)*64 + d];
            Vt[d*SVT + kx] = val;
        }
    }

    for (int idx = tid; idx < 32*29; idx += ATHR) {
        int g = idx / 29, c = idx - g*29, c8 = c << 3;
        f16x8 hv;
#pragma unroll
        for (int e = 0; e < 8; ++e) hv[e] = (f16)0.f;
        if (g < 14 || (g >= 16 && g < 30)) {
#pragma unroll
            for (int e = 0; e < 8; ++e) {
                int j = c8 + e;
                if (j >= 1 && j <= 196) {
                    int jm = j - 1;
                    int gv = (int)div14((unsigned)jm);
                    int gh = jm - gv*14;
                    if ((g < 14 && gv == g) || (g >= 16 && gh == g - 16))
                        hv[e] = (f16)1.f;
                }
            }
        }
        *(f16x8*)&Gt[g*SGT + c8] = hv;
    }
    __syncthreads();

    const int src0 = ((l >> 4) & 1) * 32 + lr;
    const int src1 = src0 + 16;

    {
        const int tt = w;                            // one tile per wave
        const int i0 = tt * 16;
        const int iq = i0 + lr;
        const int iqc = (iq > 196) ? 196 : iq;
        const f16* qsrc = Qp + iqc*64 + lq*8;
        f16x8 qf0 = *(const f16x8*)qsrc;
        f16x8 qf1 = *(const f16x8*)(qsrc + 32);

        __builtin_amdgcn_s_setprio(1);
        f32x4 pacc[4];
#pragma unroll
        for (int ct = 0; ct < 4; ++ct) {
            f32x4 a; a[0]=0.f; a[1]=0.f; a[2]=0.f; a[3]=0.f;
            const int krow = (13+ct)*16 + lr;
            f16x8 kf0 = *(f16x8*)&Kle[krow*SKE + lq*8];
            f16x8 kf1 = *(f16x8*)&Kle[krow*SKE + 32 + lq*8];
            a = __builtin_amdgcn_mfma_f32_16x16x32_f16(kf0, qf0, a, 0, 0, 0);
            a = __builtin_amdgcn_mfma_f32_16x16x32_f16(kf1, qf1, a, 0, 0, 0);
            pacc[ct] = a;
        }
        __builtin_amdgcn_s_setprio(0);
#pragma unroll
        for (int ct = 0; ct < 4; ++ct)
#pragma unroll
            for (int rg = 0; rg < 4; ++rg)
                wsh[lr*SWS + ct*16 + lq*4 + rg] = (f16)pacc[ct][rg];
        wfence();

        int id_ = 0, ih_ = 0;
        const bool qcls = (iq == 0);
        if (iq > 0) { unsigned v = div14((unsigned)(iq-1)); id_ = (int)v; ih_ = (iq-1) - (int)v*14; }
        f16x8 qcf;
#pragma unroll
        for (int e = 0; e < 8; ++e) {
            int g = lq*8 + e;
            int toff;
            if (g < 14)       toff = qcls ? 0 : (g - id_ + 15);
            else if (g == 14) toff = 0;
            else if (g == 15) toff = 63;
            else if (g < 30)  toff = qcls ? 32 : (32 + (g-16) - ih_ + 15);
            else if (g == 30) toff = 32;
            else              toff = 63;
            qcf[e] = wsh[lr*SWS + toff];
        }

        f32x4 acc[13];
        __builtin_amdgcn_s_setprio(1);
#pragma unroll
        for (int ct = 0; ct < 13; ++ct) {
            f32x4 a; a[0]=0.f; a[1]=0.f; a[2]=0.f; a[3]=0.f;
            const int krow = ct*16 + lr;
            f16x8 kf0 = *(f16x8*)&Kle[krow*SKE + lq*8];
            f16x8 kf1 = *(f16x8*)&Kle[krow*SKE + 32 + lq*8];
            f16x8 gf  = *(f16x8*)&Kle[krow*SKE + 64 + lq*8];
            a = __builtin_amdgcn_mfma_f32_16x16x32_f16(kf0, qf0, a, 0, 0, 0);
            a = __builtin_amdgcn_mfma_f32_16x16x32_f16(kf1, qf1, a, 0, 0, 0);
            a = __builtin_amdgcn_mfma_f32_16x16x32_f16(gf,  qcf, a, 0, 0, 0);
            acc[ct] = a;
        }
        __builtin_amdgcn_s_setprio(0);

#pragma unroll
        for (int rg = 0; rg < 4; ++rg)
            if (lq*4 + rg > 4) acc[12][rg] = -1e30f;

        float m = -1e30f;
#pragma unroll
        for (int ct = 0; ct < 13; ++ct)
#pragma unroll
            for (int rg = 0; rg < 4; ++rg) m = fmaxf(m, acc[ct][rg]);
        m = fmaxf(m, __shfl_xor(m, 16));
        m = fmaxf(m, __shfl_xor(m, 32));
        const float C1 = 0.125f * 1.44269504088896f;
        const float nm = -m * C1;
        float ssum = 0.f;
#pragma unroll
        for (int ct = 0; ct < 13; ++ct)
#pragma unroll
            for (int rg = 0; rg < 4; ++rg) {
                float p = exp2f(fmaf(acc[ct][rg], C1, nm));
                acc[ct][rg] = p; ssum += p;
            }
        ssum += __shfl_xor(ssum, 16);
        ssum += __shfl_xor(ssum, 32);
        const float inv = 1.f / ssum;
        const float pn00 = acc[0][0] * inv;

        unsigned pk[13][2];
#pragma unroll
        for (int ct = 0; ct < 13; ++ct) {
            union { f16x4 hh; unsigned u[2]; } t;
            t.hh[0] = (f16)(acc[ct][0] * inv);
            t.hh[1] = (f16)(acc[ct][1] * inv);
            t.hh[2] = (f16)(acc[ct][2] * inv);
            t.hh[3] = (f16)(acc[ct][3] * inv);
            pk[ct][0] = t.u[0]; pk[ct][1] = t.u[1];
        }

        f16x8 pa[7];
#pragma unroll
        for (int kc = 0; kc < 7; ++kc) {
            const int ctA = 2*kc;
            const int ctB = (kc == 6) ? 12 : 2*kc + 1;
            unsigned A0 = (unsigned)__shfl((int)pk[ctA][0], src0);
            unsigned A1 = (unsigned)__shfl((int)pk[ctA][1], src0);
            unsigned A2 = (unsigned)__shfl((int)pk[ctA][0], src1);
            unsigned A3 = (unsigned)__shfl((int)pk[ctA][1], src1);
            unsigned B0 = (unsigned)__shfl((int)pk[ctB][0], src0);
            unsigned B1 = (unsigned)__shfl((int)pk[ctB][1], src0);
            unsigned B2 = (unsigned)__shfl((int)pk[ctB][0], src1);
            unsigned B3 = (unsigned)__shfl((int)pk[ctB][1], src1);
            bool hiHalf = (lq >= 2);
            union { unsigned u[4]; f16x8 v; } f;
            f.u[0] = hiHalf ? B0 : A0;
            f.u[1] = hiHalf ? B1 : A1;
            f.u[2] = hiHalf ? B2 : A2;
            f.u[3] = hiHalf ? B3 : A3;
            if (kc == 6 && hiHalf) { f.u[0]=0; f.u[1]=0; f.u[2]=0; f.u[3]=0; }
            pa[kc] = f.v;
        }

        f32x4 gacc[2];
#pragma unroll
        for (int ct = 0; ct < 2; ++ct) { gacc[ct][0]=0.f; gacc[ct][1]=0.f; gacc[ct][2]=0.f; gacc[ct][3]=0.f; }
        __builtin_amdgcn_s_setprio(1);
#pragma unroll
        for (int kc = 0; kc < 7; ++kc) {
#pragma unroll
            for (int ct = 0; ct < 2; ++ct) {
                f16x8 gf = *(f16x8*)&Gt[(ct*16 + lr)*SGT + kc*32 + lq*8];
                gacc[ct] = __builtin_amdgcn_mfma_f32_16x16x32_f16(pa[kc], gf, gacc[ct], 0, 0, 0);
            }
        }
        __builtin_amdgcn_s_setprio(0);

#pragma unroll
        for (int z = 0; z < 2; ++z) {
            int zi = z*64 + l;
            int zr = zi >> 3, zc = (zi & 7) << 3;
            f16x8 zz;
#pragma unroll
            for (int e = 0; e < 8; ++e) zz[e] = (f16)0.f;
            *(f16x8*)&wsh[zr*SWS + zc] = zz;
        }
        wfence();
#pragma unroll
        for (int rg = 0; rg < 4; ++rg) {
            int il = lq*4 + rg;
            int is_ = i0 + il;
            if (lr < 14 && is_ > 0) {
                unsigned v = div14((unsigned)(is_-1));
                int id2 = (int)v, ih2 = (is_-1) - (int)v*14;
                wsh[il*SWS + (lr - id2 + 15)]      = (f16)gacc[0][rg];
                wsh[il*SWS + 30 + (lr - ih2 + 15)] = (f16)gacc[1][rg];
            }
        }
        if (lq == 0 && !(i0 == 0 && lr == 0)) {
            wsh[lr*SWS + 0]  = (f16)pn00;
            wsh[lr*SWS + 30] = (f16)pn00;
        }
        if (i0 == 0) {
            float sv = (lq == 0) ? gacc[0][0] : 0.f;
            float sh = (lq == 0) ? gacc[1][0] : 0.f;
            sv += __shfl_xor(sv, 1); sv += __shfl_xor(sv, 2);
            sv += __shfl_xor(sv, 4); sv += __shfl_xor(sv, 8);
            sh += __shfl_xor(sh, 1); sh += __shfl_xor(sh, 2);
            sh += __shfl_xor(sh, 4); sh += __shfl_xor(sh, 8);
            if (l == 0) {
                wsh[0]  = (f16)(sv + pn00);
                wsh[30] = (f16)(sh + pn00);
            }
        }
        wfence();

        f16x8 sfr[2];
#pragma unroll
        for (int kc2 = 0; kc2 < 2; ++kc2)
            sfr[kc2] = *(f16x8*)&wsh[lr*SWS + kc2*32 + lq*8];

        f32x4 oacc[4];
#pragma unroll
        for (int ct = 0; ct < 4; ++ct) { oacc[ct][0]=0.f; oacc[ct][1]=0.f; oacc[ct][2]=0.f; oacc[ct][3]=0.f; }
        __builtin_amdgcn_s_setprio(1);
        const int swz = (lr & 7) << 3;
#pragma unroll
        for (int kc = 0; kc < 7; ++kc) {
#pragma unroll
            for (int ct = 0; ct < 4; ++ct) {
                f16x8 vf = *(f16x8*)&Vt[(ct*16 + lr)*SVT + ((kc*32 + lq*8) ^ swz)];
                oacc[ct] = __builtin_amdgcn_mfma_f32_16x16x32_f16(pa[kc], vf, oacc[ct], 0, 0, 0);
            }
        }
#pragma unroll
        for (int kc2 = 0; kc2 < 2; ++kc2) {
#pragma unroll
            for (int ct = 0; ct < 4; ++ct) {
                f16x8 vf = *(f16x8*)&Vt[(ct*16 + lr)*SVT + ((208 + kc2*32 + lq*8) ^ swz)];
                oacc[ct] = __builtin_amdgcn_mfma_f32_16x16x32_f16(sfr[kc2], vf, oacc[ct], 0, 0, 0);
            }
        }
        __builtin_amdgcn_s_setprio(0);

#pragma unroll
        for (int ct = 0; ct < 4; ++ct)
#pragma unroll
            for (int rg = 0; rg < 4; ++rg) {
                int io = i0 + lq*4 + rg;
                if (io < NTOK) {
                    int d = ct*16 + lr;
                    o_ws[((size_t)(b * NTOK + io) * NH + h) * HDIM + d] = (f16)oacc[ct][rg];
                }
            }
    }
}

extern "C" void kernel_launch(void* const* d_in, const int* in_sizes, int n_in,
                              void* d_out, int out_size, void* d_ws, size_t ws_size,
                              hipStream_t stream)
{
    const float* x     = (const float*)d_in[0];
    const float* wq    = (const float*)d_in[1];
    const float* wk    = (const float*)d_in[2];
    const float* wv    = (const float*)d_in[3];
    const float* wproj = (const float*)d_in[4];
    const float* bproj = (const float*)d_in[5];
    const float* rkv   = (const float*)d_in[6];
    const float* rkh   = (const float*)d_in[7];
    const float* rvv   = (const float*)d_in[8];
    const float* rvh   = (const float*)d_in[9];

    f16* ws = (f16*)d_ws;
    const size_t sz = (size_t)MROWS * EDIM;
    f16* xh    = ws;
    f16* qh    = xh + sz;
    f16* kh    = qh + sz;
    f16* vh    = kh + sz;
    f16* oh    = vh + sz;
    f16* wqkvT = oh + sz;
    f16* wpT   = wqkvT + (size_t)3*EDIM*EDIM;

    convert_x  <<<4728, 256, 0, stream>>>(x, xh);
    transpose_w<<<dim3(12, 12, 4), 256, 0, stream>>>(wq, wk, wv, wproj, wqkvT, wpT);
    gemm256    <<<50*9, 512, 0, stream>>>(xh, wqkvT, qh, kh, vh,
                                          nullptr, nullptr, 0, 9);
    attn_mfma  <<<NB * NH, ATHR, 0, stream>>>(qh, kh, vh,
                                              rkv, rkh, rvv, rvh, oh);
    gemm256    <<<50*3, 512, 0, stream>>>(oh, wpT, nullptr, nullptr, nullptr,
                                          (float*)d_out, bproj, 1, 3);
}

// Round 10
// 152.734 us; speedup vs baseline: 1.1931x; 1.0097x over previous
//
#include <hip/hip_runtime.h>
#include <math.h>

typedef _Float16 f16;
typedef __attribute__((ext_vector_type(8))) _Float16 f16x8;
typedef __attribute__((ext_vector_type(4))) _Float16 f16x4;
typedef __attribute__((ext_vector_type(4))) float f32x4;

#define NH 12
#define HDIM 64
#define NTOK 197
#define EDIM 768
#define NB 64
#define MROWS (NB*NTOK)   // 12608

__device__ __forceinline__ void wfence() {
    asm volatile("s_waitcnt lgkmcnt(0)" ::: "memory");
    __builtin_amdgcn_sched_barrier(0);
    __builtin_amdgcn_wave_barrier();
}

__device__ __forceinline__ unsigned div14(unsigned n) { return (n * 4682u) >> 16; }  // exact n<=206

__device__ __forceinline__ void gload16(const f16* g, f16* lds_base) {
    __builtin_amdgcn_global_load_lds(
        (const __attribute__((address_space(1))) void*)g,
        (__attribute__((address_space(3))) void*)lds_base, 16, 0, 0);
}

// ---------------------------------------------------------------------------
// x [12608x768] f32 -> f16.  (HBM-bound — at roofline.)
// ---------------------------------------------------------------------------
__global__ __launch_bounds__(256) void convert_x(
    const float* __restrict__ x, f16* __restrict__ xh)
{
    int idx = blockIdx.x * 256 + threadIdx.x;
    const float4* s = (const float4*)x + (size_t)idx * 2;
    float4 a = s[0], b = s[1];
    f16x8 h;
    h[0]=(f16)a.x; h[1]=(f16)a.y; h[2]=(f16)a.z; h[3]=(f16)a.w;
    h[4]=(f16)b.x; h[5]=(f16)b.y; h[6]=(f16)b.z; h[7]=(f16)b.w;
    *(f16x8*)(xh + (size_t)idx * 8) = h;
}

// ---------------------------------------------------------------------------
// LDS-tiled transpose + f16: wT[n][k] = (f16)w[k][n].
// ---------------------------------------------------------------------------
__global__ __launch_bounds__(256) void transpose_w(
    const float* __restrict__ wq, const float* __restrict__ wk,
    const float* __restrict__ wv, const float* __restrict__ wp,
    f16* __restrict__ wqkvT, f16* __restrict__ wpT)
{
    __shared__ float T[64][65];
    int m = blockIdx.z;
    const float* src = (m==0)?wq:(m==1)?wk:(m==2)?wv:wp;
    int k0 = blockIdx.x * 64, n0 = blockIdx.y * 64;
    int cidx = threadIdx.x & 63, r4 = threadIdx.x >> 6;
#pragma unroll
    for (int rr = 0; rr < 16; ++rr) {
        int kl = rr*4 + r4;
        T[kl][cidx] = src[(size_t)(k0+kl)*EDIM + n0 + cidx];
    }
    __syncthreads();
    f16* dst = (m < 3) ? (wqkvT + (size_t)m*EDIM*EDIM) : wpT;
#pragma unroll
    for (int rr = 0; rr < 16; ++rr) {
        int nl = rr*4 + r4;
        dst[(size_t)(n0+nl)*EDIM + k0 + cidx] = (f16)T[cidx][nl];
    }
}

// ---------------------------------------------------------------------------
// One-time static table builder (identical content for all 768 attn blocks —
// previously rebuilt per block with div14-heavy branchy VALU):
//   gA[272][104]  Kle template: rows 208-237 rk_v, 240-269 rk_h (cols 0-63);
//                 Gt2 one-hots at cols 64-95 for rows 0-207; zeros elsewhere.
//   gt_buf[32][232] group one-hot for the group-sum GEMM.
// ---------------------------------------------------------------------------
__global__ __launch_bounds__(256) void prep_static(
    const float* __restrict__ rkv, const float* __restrict__ rkh,
    f16* __restrict__ gA, f16* __restrict__ gt_buf)
{
    int t = blockIdx.x * 256 + threadIdx.x;
    int stride = gridDim.x * 256;
    for (int i = t; i < 272*104; i += stride) {
        int row = i / 104, c = i - row*104;
        f16 v = (f16)0.f;
        if (c < 64) {
            if (row >= 208 && row < 238)      v = (f16)rkv[(row-208)*64 + c];
            else if (row >= 240 && row < 270) v = (f16)rkh[(row-240)*64 + c];
        } else if (c < 96 && row < 208) {
            int g = c - 64;
            if (row == 0) { if (g == 14 || g == 30) v = (f16)1.f; }
            else if (row <= 196) {
                int rm = row - 1;
                int gv = (int)div14((unsigned)rm), gh = rm - gv*14;
                if (g == gv || g == 16 + gh) v = (f16)1.f;
            }
        }
        gA[i] = v;
    }
    for (int i = t; i < 32*232; i += stride) {
        int g = i / 232, j = i - g*232;
        f16 v = (f16)0.f;
        if (j >= 1 && j <= 196) {
            int jm = j - 1;
            int gv = (int)div14((unsigned)jm), gh = jm - gv*14;
            if ((g < 14 && gv == g) || (g >= 16 && g < 30 && gh == g - 16))
                v = (f16)1.f;
        }
        gt_buf[i] = v;
    }
}

// ---------------------------------------------------------------------------
// 256x256-tile f16 MFMA GEMM, 8 waves, dbuf global_load_lds + counted-drain
// pipeline (unchanged from round 8).
// ---------------------------------------------------------------------------
__global__ __launch_bounds__(512, 2) void gemm256(
    const f16* __restrict__ A, const f16* __restrict__ Bt,
    f16* __restrict__ q_o, f16* __restrict__ k_o, f16* __restrict__ v_o,
    float* __restrict__ p_o, const float* __restrict__ bias, int mode, int nxb)
{
    __shared__ f16 lds[4*16384];

    const int tid = threadIdx.x;
    const int l = tid & 63, w = tid >> 6;
    const int lr = l & 15, lq = l >> 4;
    const int wr = w >> 2, wc = w & 3;

    const int nwg = gridDim.x, orig = blockIdx.x;
    const int xcd = orig & 7, qc = nwg >> 3, rc = nwg & 7;
    const int wgid = (xcd < rc ? xcd*(qc+1) : rc*(qc+1) + (xcd-rc)*qc) + (orig >> 3);
    const int mband = wgid / nxb, nband = wgid - mband*nxb;
    const int m0 = mband << 8, n0 = nband << 8;

    const int scol = (((tid & 7) ^ ((tid >> 3) & 7)) << 3);
    const f16* aG[4]; const f16* bG[4];
#pragma unroll
    for (int p = 0; p < 4; ++p) {
        int rt = p*64 + (tid >> 3);
        int ra = m0 + rt; if (ra >= MROWS) ra = MROWS - 1;
        aG[p] = A  + (size_t)ra * EDIM + scol;
        bG[p] = Bt + (size_t)(n0 + rt) * EDIM + scol;
    }
    const int lbase = w * 512;

    f32x4 acc[8][4];
#pragma unroll
    for (int mt = 0; mt < 8; ++mt)
#pragma unroll
        for (int nt = 0; nt < 4; ++nt) {
            acc[mt][nt][0]=0.f; acc[mt][nt][1]=0.f;
            acc[mt][nt][2]=0.f; acc[mt][nt][3]=0.f;
        }

#pragma unroll
    for (int p = 0; p < 4; ++p) {
        gload16(aG[p], &lds[p*4096 + lbase]);
        gload16(bG[p], &lds[32768 + p*4096 + lbase]);
    }
    asm volatile("s_waitcnt vmcnt(0)" ::: "memory");
    __builtin_amdgcn_sched_barrier(0);
    __builtin_amdgcn_s_barrier();

    const int swz = (lr & 7) << 3;
    int cur = 0;
    for (int kt = 0; kt < 12; ++kt) {
        if (kt < 11) {
            const int ko = (kt + 1) * 64;
            const int nb = (cur ^ 1) * 16384;
#pragma unroll
            for (int p = 0; p < 4; ++p) {
                gload16(aG[p] + ko, &lds[nb + p*4096 + lbase]);
                gload16(bG[p] + ko, &lds[32768 + nb + p*4096 + lbase]);
            }
        }
        __builtin_amdgcn_sched_barrier(0);
        const f16* Ab = &lds[cur * 16384];
        const f16* Bb = &lds[32768 + cur * 16384];
#pragma unroll
        for (int ks = 0; ks < 2; ++ks) {
            const int kb = (ks*32 + lq*8) ^ swz;
            f16x8 bf[4];
#pragma unroll
            for (int nt = 0; nt < 4; ++nt)
                bf[nt] = *(const f16x8*)&Bb[(wc*64 + nt*16 + lr)*64 + kb];
#pragma unroll
            for (int mt = 0; mt < 8; ++mt) {
                f16x8 af = *(const f16x8*)&Ab[(wr*128 + mt*16 + lr)*64 + kb];
#pragma unroll
                for (int nt = 0; nt < 4; ++nt)
                    acc[mt][nt] = __builtin_amdgcn_mfma_f32_16x16x32_f16(
                        af, bf[nt], acc[mt][nt], 0, 0, 0);
            }
        }
        asm volatile("s_waitcnt vmcnt(0)" ::: "memory");
        __builtin_amdgcn_sched_barrier(0);
        __builtin_amdgcn_s_barrier();
        cur ^= 1;
    }

    if (mode == 0) {
        const int mat   = n0 / EDIM;
        const int hbase = ((n0 % EDIM) >> 6) + wc;
        f16* dst = (mat == 0) ? q_o : (mat == 1) ? k_o : v_o;
        f16* scr = &lds[w * 2304];
#pragma unroll
        for (int mt2 = 0; mt2 < 4; ++mt2) {
#pragma unroll
            for (int mtp = 0; mtp < 2; ++mtp) {
                const int mt = mt2*2 + mtp;
#pragma unroll
                for (int nt = 0; nt < 4; ++nt)
#pragma unroll
                    for (int rg = 0; rg < 4; ++rg)
                        scr[(mtp*16 + lq*4 + rg)*72 + nt*16 + lr] = (f16)acc[mt][nt][rg];
            }
            wfence();
#pragma unroll
            for (int i = 0; i < 4; ++i) {
                int row = (l >> 3) + i*8;
                f16x8 v = *(const f16x8*)&scr[row*72 + (l & 7)*8];
                int R = m0 + wr*128 + mt2*32 + row;
                if (R < MROWS) {
                    int bb = R / NTOK, nn = R - bb*NTOK;
                    *(f16x8*)&dst[((size_t)(bb*NH + hbase)*NTOK + nn)*HDIM + (l & 7)*8] = v;
                }
            }
            wfence();
        }
    } else {
#pragma unroll
        for (int mt = 0; mt < 8; ++mt)
#pragma unroll
            for (int rg = 0; rg < 4; ++rg) {
                int R = m0 + wr*128 + mt*16 + lq*4 + rg;
                if (R < MROWS) {
                    float* base = p_o + (size_t)R * EDIM + n0 + wc*64;
#pragma unroll
                    for (int nt = 0; nt < 4; ++nt) {
                        int c = nt*16 + lr;
                        base[c] = acc[mt][nt][rg] + bias[n0 + wc*64 + c];
                    }
                }
            }
    }
}

// ---------------------------------------------------------------------------
// MFMA fused attention v5: 13 waves, one 16-query tile per wave.
// Staging is now pure vectorized copies (static tables precomputed by
// prep_static). Compute phase identical to rounds 6-9.
// ---------------------------------------------------------------------------
#define SKE 104
#define SVT 320
#define SGT 232
#define SWS 72
#define ATHR 832

__global__ __launch_bounds__(ATHR, 1) void attn_mfma(
    const f16* __restrict__ q_ws, const f16* __restrict__ k_ws,
    const f16* __restrict__ v_ws,
    const float* __restrict__ rvv, const float* __restrict__ rvh,
    const f16* __restrict__ gA, const f16* __restrict__ gt_buf,
    f16* __restrict__ o_ws)
{
    __shared__ f16 Kle[272*SKE];     // 56576 B
    __shared__ f16 Vt[64*SVT];       // 40960 B
    __shared__ f16 Gt[32*SGT];       // 14848 B
    __shared__ f16 WSh[13*16*SWS];   // 29952 B  (total 142336 B)

    const int tid = threadIdx.x;
    const int w = tid >> 6, l = tid & 63;
    const int lr = l & 15, lq = l >> 4;
    const int bh = blockIdx.x;
    const int b = bh / NH, h = bh - b * NH;
    const f16* Qp = q_ws + (size_t)bh * NTOK * HDIM;
    const f16* Kp = k_ws + (size_t)bh * NTOK * HDIM;
    const f16* Vp = v_ws + (size_t)bh * NTOK * HDIM;
    f16* wsh = &WSh[w * 16 * SWS];

    // ---- (a1) K rows 0-196, cols 0-63: copy from Kp ----
    for (int idx = tid; idx < 197*8; idx += ATHR) {
        int row = idx >> 3, c8 = (idx & 7) << 3;
        *(f16x8*)&Kle[row*SKE + c8] = *(const f16x8*)(Kp + row*64 + c8);
    }
    // ---- (a2) rows 0-196, cols 64-103: copy from template ----
    for (int idx = tid; idx < 197*5; idx += ATHR) {
        int row = idx / 5, c = idx - row*5;
        int off = row*SKE + 64 + c*8;
        *(f16x8*)&Kle[off] = *(const f16x8*)(gA + off);
    }
    // ---- (b) rows 197-271 full: copy from template ----
    for (int idx = tid; idx < 75*13; idx += ATHR) {
        int off = 197*SKE + idx*8;
        *(f16x8*)&Kle[off] = *(const f16x8*)(gA + off);
    }
    // ---- Gt: copy from template ----
    for (int idx = tid; idx < 32*29; idx += ATHR) {
        int off = idx*8;
        *(f16x8*)&Gt[off] = *(const f16x8*)(gt_buf + off);
    }
    // ---- Vt transpose staging (per-(b,h), unchanged) ----
    for (int idx = tid; idx < 8*SVT; idx += ATHR) {
        int dlow = idx & 7, k = idx >> 3;
        int kx = k ^ (dlow << 3);
        bool isV = (k < NTOK), isA = (k >= 208 && k < 238), isB = (k >= 238 && k < 268);
#pragma unroll
        for (int e = 0; e < 8; ++e) {
            int d = (e << 3) + dlow;
            f16 val = (f16)0.f;
            if (isV)      val = Vp[k*64 + d];
            else if (isA) val = (f16)rvv[(k-208)*64 + d];
            else if (isB) val = (f16)rvh[(k-238)*64 + d];
            Vt[d*SVT + kx] = val;
        }
    }
    __syncthreads();

    const int src0 = ((l >> 4) & 1) * 32 + lr;
    const int src1 = src0 + 16;

    {
        const int tt = w;
        const int i0 = tt * 16;
        const int iq = i0 + lr;
        const int iqc = (iq > 196) ? 196 : iq;
        const f16* qsrc = Qp + iqc*64 + lq*8;
        f16x8 qf0 = *(const f16x8*)qsrc;
        f16x8 qf1 = *(const f16x8*)(qsrc + 32);

        __builtin_amdgcn_s_setprio(1);
        f32x4 pacc[4];
#pragma unroll
        for (int ct = 0; ct < 4; ++ct) {
            f32x4 a; a[0]=0.f; a[1]=0.f; a[2]=0.f; a[3]=0.f;
            const int krow = (13+ct)*16 + lr;
            f16x8 kf0 = *(f16x8*)&Kle[krow*SKE + lq*8];
            f16x8 kf1 = *(f16x8*)&Kle[krow*SKE + 32 + lq*8];
            a = __builtin_amdgcn_mfma_f32_16x16x32_f16(kf0, qf0, a, 0, 0, 0);
            a = __builtin_amdgcn_mfma_f32_16x16x32_f16(kf1, qf1, a, 0, 0, 0);
            pacc[ct] = a;
        }
        __builtin_amdgcn_s_setprio(0);
#pragma unroll
        for (int ct = 0; ct < 4; ++ct)
#pragma unroll
            for (int rg = 0; rg < 4; ++rg)
                wsh[lr*SWS + ct*16 + lq*4 + rg] = (f16)pacc[ct][rg];
        wfence();

        int id_ = 0, ih_ = 0;
        const bool qcls = (iq == 0);
        if (iq > 0) { unsigned v = div14((unsigned)(iq-1)); id_ = (int)v; ih_ = (iq-1) - (int)v*14; }
        f16x8 qcf;
#pragma unroll
        for (int e = 0; e < 8; ++e) {
            int g = lq*8 + e;
            int toff;
            if (g < 14)       toff = qcls ? 0 : (g - id_ + 15);
            else if (g == 14) toff = 0;
            else if (g == 15) toff = 63;
            else if (g < 30)  toff = qcls ? 32 : (32 + (g-16) - ih_ + 15);
            else if (g == 30) toff = 32;
            else              toff = 63;
            qcf[e] = wsh[lr*SWS + toff];
        }

        f32x4 acc[13];
        __builtin_amdgcn_s_setprio(1);
#pragma unroll
        for (int ct = 0; ct < 13; ++ct) {
            f32x4 a; a[0]=0.f; a[1]=0.f; a[2]=0.f; a[3]=0.f;
            const int krow = ct*16 + lr;
            f16x8 kf0 = *(f16x8*)&Kle[krow*SKE + lq*8];
            f16x8 kf1 = *(f16x8*)&Kle[krow*SKE + 32 + lq*8];
            f16x8 gf  = *(f16x8*)&Kle[krow*SKE + 64 + lq*8];
            a = __builtin_amdgcn_mfma_f32_16x16x32_f16(kf0, qf0, a, 0, 0, 0);
            a = __builtin_amdgcn_mfma_f32_16x16x32_f16(kf1, qf1, a, 0, 0, 0);
            a = __builtin_amdgcn_mfma_f32_16x16x32_f16(gf,  qcf, a, 0, 0, 0);
            acc[ct] = a;
        }
        __builtin_amdgcn_s_setprio(0);

#pragma unroll
        for (int rg = 0; rg < 4; ++rg)
            if (lq*4 + rg > 4) acc[12][rg] = -1e30f;

        float m = -1e30f;
#pragma unroll
        for (int ct = 0; ct < 13; ++ct)
#pragma unroll
            for (int rg = 0; rg < 4; ++rg) m = fmaxf(m, acc[ct][rg]);
        m = fmaxf(m, __shfl_xor(m, 16));
        m = fmaxf(m, __shfl_xor(m, 32));
        const float C1 = 0.125f * 1.44269504088896f;
        const float nm = -m * C1;
        float ssum = 0.f;
#pragma unroll
        for (int ct = 0; ct < 13; ++ct)
#pragma unroll
            for (int rg = 0; rg < 4; ++rg) {
                float p = exp2f(fmaf(acc[ct][rg], C1, nm));
                acc[ct][rg] = p; ssum += p;
            }
        ssum += __shfl_xor(ssum, 16);
        ssum += __shfl_xor(ssum, 32);
        const float inv = 1.f / ssum;
        const float pn00 = acc[0][0] * inv;

        unsigned pk[13][2];
#pragma unroll
        for (int ct = 0; ct < 13; ++ct) {
            union { f16x4 hh; unsigned u[2]; } t;
            t.hh[0] = (f16)(acc[ct][0] * inv);
            t.hh[1] = (f16)(acc[ct][1] * inv);
            t.hh[2] = (f16)(acc[ct][2] * inv);
            t.hh[3] = (f16)(acc[ct][3] * inv);
            pk[ct][0] = t.u[0]; pk[ct][1] = t.u[1];
        }

        f16x8 pa[7];
#pragma unroll
        for (int kc = 0; kc < 7; ++kc) {
            const int ctA = 2*kc;
            const int ctB = (kc == 6) ? 12 : 2*kc + 1;
            unsigned A0 = (unsigned)__shfl((int)pk[ctA][0], src0);
            unsigned A1 = (unsigned)__shfl((int)pk[ctA][1], src0);
            unsigned A2 = (unsigned)__shfl((int)pk[ctA][0], src1);
            unsigned A3 = (unsigned)__shfl((int)pk[ctA][1], src1);
            unsigned B0 = (unsigned)__shfl((int)pk[ctB][0], src0);
            unsigned B1 = (unsigned)__shfl((int)pk[ctB][1], src0);
            unsigned B2 = (unsigned)__shfl((int)pk[ctB][0], src1);
            unsigned B3 = (unsigned)__shfl((int)pk[ctB][1], src1);
            bool hiHalf = (lq >= 2);
            union { unsigned u[4]; f16x8 v; } f;
            f.u[0] = hiHalf ? B0 : A0;
            f.u[1] = hiHalf ? B1 : A1;
            f.u[2] = hiHalf ? B2 : A2;
            f.u[3] = hiHalf ? B3 : A3;
            if (kc == 6 && hiHalf) { f.u[0]=0; f.u[1]=0; f.u[2]=0; f.u[3]=0; }
            pa[kc] = f.v;
        }

        f32x4 gacc[2];
#pragma unroll
        for (int ct = 0; ct < 2; ++ct) { gacc[ct][0]=0.f; gacc[ct][1]=0.f; gacc[ct][2]=0.f; gacc[ct][3]=0.f; }
        __builtin_amdgcn_s_setprio(1);
#pragma unroll
        for (int kc = 0; kc < 7; ++kc) {
#pragma unroll
            for (int ct = 0; ct < 2; ++ct) {
                f16x8 gf = *(f16x8*)&Gt[(ct*16 + lr)*SGT + kc*32 + lq*8];
                gacc[ct] = __builtin_amdgcn_mfma_f32_16x16x32_f16(pa[kc], gf, gacc[ct], 0, 0, 0);
            }
        }
        __builtin_amdgcn_s_setprio(0);

#pragma unroll
        for (int z = 0; z < 2; ++z) {
            int zi = z*64 + l;
            int zr = zi >> 3, zc = (zi & 7) << 3;
            f16x8 zz;
#pragma unroll
            for (int e = 0; e < 8; ++e) zz[e] = (f16)0.f;
            *(f16x8*)&wsh[zr*SWS + zc] = zz;
        }
        wfence();
#pragma unroll
        for (int rg = 0; rg < 4; ++rg) {
            int il = lq*4 + rg;
            int is_ = i0 + il;
            if (lr < 14 && is_ > 0) {
                unsigned v = div14((unsigned)(is_-1));
                int id2 = (int)v, ih2 = (is_-1) - (int)v*14;
                wsh[il*SWS + (lr - id2 + 15)]      = (f16)gacc[0][rg];
                wsh[il*SWS + 30 + (lr - ih2 + 15)] = (f16)gacc[1][rg];
            }
        }
        if (lq == 0 && !(i0 == 0 && lr == 0)) {
            wsh[lr*SWS + 0]  = (f16)pn00;
            wsh[lr*SWS + 30] = (f16)pn00;
        }
        if (i0 == 0) {
            float sv = (lq == 0) ? gacc[0][0] : 0.f;
            float sh = (lq == 0) ? gacc[1][0] : 0.f;
            sv += __shfl_xor(sv, 1); sv += __shfl_xor(sv, 2);
            sv += __shfl_xor(sv, 4); sv += __shfl_xor(sv, 8);
            sh += __shfl_xor(sh, 1); sh += __shfl_xor(sh, 2);
            sh += __shfl_xor(sh, 4); sh += __shfl_xor(sh, 8);
            if (l == 0) {
                wsh[0]  = (f16)(sv + pn00);
                wsh[30] = (f16)(sh + pn00);
            }
        }
        wfence();

        f16x8 sfr[2];
#pragma unroll
        for (int kc2 = 0; kc2 < 2; ++kc2)
            sfr[kc2] = *(f16x8*)&wsh[lr*SWS + kc2*32 + lq*8];

        f32x4 oacc[4];
#pragma unroll
        for (int ct = 0; ct < 4; ++ct) { oacc[ct][0]=0.f; oacc[ct][1]=0.f; oacc[ct][2]=0.f; oacc[ct][3]=0.f; }
        __builtin_amdgcn_s_setprio(1);
        const int swz = (lr & 7) << 3;
#pragma unroll
        for (int kc = 0; kc < 7; ++kc) {
#pragma unroll
            for (int ct = 0; ct < 4; ++ct) {
                f16x8 vf = *(f16x8*)&Vt[(ct*16 + lr)*SVT + ((kc*32 + lq*8) ^ swz)];
                oacc[ct] = __builtin_amdgcn_mfma_f32_16x16x32_f16(pa[kc], vf, oacc[ct], 0, 0, 0);
            }
        }
#pragma unroll
        for (int kc2 = 0; kc2 < 2; ++kc2) {
#pragma unroll
            for (int ct = 0; ct < 4; ++ct) {
                f16x8 vf = *(f16x8*)&Vt[(ct*16 + lr)*SVT + ((208 + kc2*32 + lq*8) ^ swz)];
                oacc[ct] = __builtin_amdgcn_mfma_f32_16x16x32_f16(sfr[kc2], vf, oacc[ct], 0, 0, 0);
            }
        }
        __builtin_amdgcn_s_setprio(0);

#pragma unroll
        for (int ct = 0; ct < 4; ++ct)
#pragma unroll
            for (int rg = 0; rg < 4; ++rg) {
                int io = i0 + lq*4 + rg;
                if (io < NTOK) {
                    int d = ct*16 + lr;
                    o_ws[((size_t)(b * NTOK + io) * NH + h) * HDIM + d] = (f16)oacc[ct][rg];
                }
            }
    }
}

extern "C" void kernel_launch(void* const* d_in, const int* in_sizes, int n_in,
                              void* d_out, int out_size, void* d_ws, size_t ws_size,
                              hipStream_t stream)
{
    const float* x     = (const float*)d_in[0];
    const float* wq    = (const float*)d_in[1];
    const float* wk    = (const float*)d_in[2];
    const float* wv    = (const float*)d_in[3];
    const float* wproj = (const float*)d_in[4];
    const float* bproj = (const float*)d_in[5];
    const float* rkv   = (const float*)d_in[6];
    const float* rkh   = (const float*)d_in[7];
    const float* rvv   = (const float*)d_in[8];
    const float* rvh   = (const float*)d_in[9];

    f16* ws = (f16*)d_ws;
    const size_t sz = (size_t)MROWS * EDIM;
    f16* xh    = ws;
    f16* qh    = xh + sz;
    f16* kh    = qh + sz;
    f16* vh    = kh + sz;
    f16* oh    = vh + sz;
    f16* wqkvT = oh + sz;                          // 3*768*768
    f16* wpT   = wqkvT + (size_t)3*EDIM*EDIM;      // 768*768
    f16* gA    = wpT   + (size_t)EDIM*EDIM;        // 272*104
    f16* gtb   = gA    + 272*104;                  // 32*232

    convert_x  <<<4728, 256, 0, stream>>>(x, xh);
    transpose_w<<<dim3(12, 12, 4), 256, 0, stream>>>(wq, wk, wv, wproj, wqkvT, wpT);
    prep_static<<<32, 256, 0, stream>>>(rkv, rkh, gA, gtb);
    gemm256    <<<50*9, 512, 0, stream>>>(xh, wqkvT, qh, kh, vh,
                                          nullptr, nullptr, 0, 9);
    attn_mfma  <<<NB * NH, ATHR, 0, stream>>>(qh, kh, vh,
                                              rvv, rvh, gA, gtb, oh);
    gemm256    <<<50*3, 512, 0, stream>>>(oh, wpT, nullptr, nullptr, nullptr,
                                          (float*)d_out, bproj, 1, 3);
}

// Round 11
// 148.146 us; speedup vs baseline: 1.2301x; 1.0310x over previous
//
#include <hip/hip_runtime.h>
#include <math.h>

typedef _Float16 f16;
typedef __attribute__((ext_vector_type(8))) _Float16 f16x8;
typedef __attribute__((ext_vector_type(4))) _Float16 f16x4;
typedef __attribute__((ext_vector_type(4))) float f32x4;

#define NH 12
#define HDIM 64
#define NTOK 197
#define EDIM 768
#define NB 64
#define MROWS (NB*NTOK)   // 12608

__device__ __forceinline__ void wfence() {
    asm volatile("s_waitcnt lgkmcnt(0)" ::: "memory");
    __builtin_amdgcn_sched_barrier(0);
    __builtin_amdgcn_wave_barrier();
}

__device__ __forceinline__ unsigned div14(unsigned n) { return (n * 4682u) >> 16; }  // exact n<=206

__device__ __forceinline__ void gload16(const f16* g, f16* lds_base) {
    __builtin_amdgcn_global_load_lds(
        (const __attribute__((address_space(1))) void*)g,
        (__attribute__((address_space(3))) void*)lds_base, 16, 0, 0);
}

// ---------------------------------------------------------------------------
// Fused prep: [0,4728) x f32->f16 | [4728,5304) weight transpose |
// [5304,5336) static rel-pos tables (stored PRE-SWIZZLED: storage col cs
// holds logical col cs ^ ((row&7)<<3), matching the attn LDS layout).
// ---------------------------------------------------------------------------
__global__ __launch_bounds__(256) void prep_all(
    const float* __restrict__ x,
    const float* __restrict__ wq, const float* __restrict__ wk,
    const float* __restrict__ wv, const float* __restrict__ wp,
    const float* __restrict__ rkv, const float* __restrict__ rkh,
    f16* __restrict__ xh, f16* __restrict__ wqkvT, f16* __restrict__ wpT,
    f16* __restrict__ gA, f16* __restrict__ gt_buf)
{
    __shared__ float T[64][65];
    const int bid = blockIdx.x;
    if (bid < 4728) {
        int idx = bid * 256 + threadIdx.x;
        const float4* s = (const float4*)x + (size_t)idx * 2;
        float4 a = s[0], b = s[1];
        f16x8 h;
        h[0]=(f16)a.x; h[1]=(f16)a.y; h[2]=(f16)a.z; h[3]=(f16)a.w;
        h[4]=(f16)b.x; h[5]=(f16)b.y; h[6]=(f16)b.z; h[7]=(f16)b.w;
        *(f16x8*)(xh + (size_t)idx * 8) = h;
    } else if (bid < 5304) {
        int b2 = bid - 4728;
        int m = b2 / 144, rem = b2 - m*144;
        const float* src = (m==0)?wq:(m==1)?wk:(m==2)?wv:wp;
        int k0 = (rem / 12) * 64, n0 = (rem % 12) * 64;
        int cidx = threadIdx.x & 63, r4 = threadIdx.x >> 6;
#pragma unroll
        for (int rr = 0; rr < 16; ++rr) {
            int kl = rr*4 + r4;
            T[kl][cidx] = src[(size_t)(k0+kl)*EDIM + n0 + cidx];
        }
        __syncthreads();
        f16* dst = (m < 3) ? (wqkvT + (size_t)m*EDIM*EDIM) : wpT;
#pragma unroll
        for (int rr = 0; rr < 16; ++rr) {
            int nl = rr*4 + r4;
            dst[(size_t)(n0+nl)*EDIM + k0 + cidx] = (f16)T[cidx][nl];
        }
    } else {
        int t = (bid - 5304) * 256 + threadIdx.x;
        const int stride = 32 * 256;
        for (int i = t; i < 272*128; i += stride) {
            int row = i >> 7, cs = i & 127;
            int c = cs ^ ((row & 7) << 3);          // logical column
            f16 v = (f16)0.f;
            if (c < 64) {
                if (row >= 208 && row < 238)      v = (f16)rkv[(row-208)*64 + c];
                else if (row >= 240 && row < 270) v = (f16)rkh[(row-240)*64 + c];
            } else if (c < 96 && row < 208) {
                int g = c - 64;
                if (row == 0) { if (g == 14 || g == 30) v = (f16)1.f; }
                else if (row <= 196) {
                    int rm = row - 1;
                    int gv = (int)div14((unsigned)rm), gh = rm - gv*14;
                    if (g == gv || g == 16 + gh) v = (f16)1.f;
                }
            }
            gA[i] = v;
        }
        for (int i = t; i < 32*256; i += stride) {
            int g = i >> 8, cs = i & 255;
            int j = cs ^ ((g & 7) << 3);            // logical column
            f16 v = (f16)0.f;
            if (j >= 1 && j <= 196) {
                int jm = j - 1;
                int gv = (int)div14((unsigned)jm), gh = jm - gv*14;
                if ((g < 14 && gv == g) || (g >= 16 && g < 30 && gh == g - 16))
                    v = (f16)1.f;
            }
            gt_buf[i] = v;
        }
    }
}

// ---------------------------------------------------------------------------
// 256x256-tile f16 MFMA GEMM (unchanged from round 8).
// ---------------------------------------------------------------------------
__global__ __launch_bounds__(512, 2) void gemm256(
    const f16* __restrict__ A, const f16* __restrict__ Bt,
    f16* __restrict__ q_o, f16* __restrict__ k_o, f16* __restrict__ v_o,
    float* __restrict__ p_o, const float* __restrict__ bias, int mode, int nxb)
{
    __shared__ f16 lds[4*16384];

    const int tid = threadIdx.x;
    const int l = tid & 63, w = tid >> 6;
    const int lr = l & 15, lq = l >> 4;
    const int wr = w >> 2, wc = w & 3;

    const int nwg = gridDim.x, orig = blockIdx.x;
    const int xcd = orig & 7, qc = nwg >> 3, rc = nwg & 7;
    const int wgid = (xcd < rc ? xcd*(qc+1) : rc*(qc+1) + (xcd-rc)*qc) + (orig >> 3);
    const int mband = wgid / nxb, nband = wgid - mband*nxb;
    const int m0 = mband << 8, n0 = nband << 8;

    const int scol = (((tid & 7) ^ ((tid >> 3) & 7)) << 3);
    const f16* aG[4]; const f16* bG[4];
#pragma unroll
    for (int p = 0; p < 4; ++p) {
        int rt = p*64 + (tid >> 3);
        int ra = m0 + rt; if (ra >= MROWS) ra = MROWS - 1;
        aG[p] = A  + (size_t)ra * EDIM + scol;
        bG[p] = Bt + (size_t)(n0 + rt) * EDIM + scol;
    }
    const int lbase = w * 512;

    f32x4 acc[8][4];
#pragma unroll
    for (int mt = 0; mt < 8; ++mt)
#pragma unroll
        for (int nt = 0; nt < 4; ++nt) {
            acc[mt][nt][0]=0.f; acc[mt][nt][1]=0.f;
            acc[mt][nt][2]=0.f; acc[mt][nt][3]=0.f;
        }

#pragma unroll
    for (int p = 0; p < 4; ++p) {
        gload16(aG[p], &lds[p*4096 + lbase]);
        gload16(bG[p], &lds[32768 + p*4096 + lbase]);
    }
    asm volatile("s_waitcnt vmcnt(0)" ::: "memory");
    __builtin_amdgcn_sched_barrier(0);
    __builtin_amdgcn_s_barrier();

    const int swz = (lr & 7) << 3;
    int cur = 0;
    for (int kt = 0; kt < 12; ++kt) {
        if (kt < 11) {
            const int ko = (kt + 1) * 64;
            const int nb = (cur ^ 1) * 16384;
#pragma unroll
            for (int p = 0; p < 4; ++p) {
                gload16(aG[p] + ko, &lds[nb + p*4096 + lbase]);
                gload16(bG[p] + ko, &lds[32768 + nb + p*4096 + lbase]);
            }
        }
        __builtin_amdgcn_sched_barrier(0);
        const f16* Ab = &lds[cur * 16384];
        const f16* Bb = &lds[32768 + cur * 16384];
#pragma unroll
        for (int ks = 0; ks < 2; ++ks) {
            const int kb = (ks*32 + lq*8) ^ swz;
            f16x8 bf[4];
#pragma unroll
            for (int nt = 0; nt < 4; ++nt)
                bf[nt] = *(const f16x8*)&Bb[(wc*64 + nt*16 + lr)*64 + kb];
#pragma unroll
            for (int mt = 0; mt < 8; ++mt) {
                f16x8 af = *(const f16x8*)&Ab[(wr*128 + mt*16 + lr)*64 + kb];
#pragma unroll
                for (int nt = 0; nt < 4; ++nt)
                    acc[mt][nt] = __builtin_amdgcn_mfma_f32_16x16x32_f16(
                        af, bf[nt], acc[mt][nt], 0, 0, 0);
            }
        }
        asm volatile("s_waitcnt vmcnt(0)" ::: "memory");
        __builtin_amdgcn_sched_barrier(0);
        __builtin_amdgcn_s_barrier();
        cur ^= 1;
    }

    if (mode == 0) {
        const int mat   = n0 / EDIM;
        const int hbase = ((n0 % EDIM) >> 6) + wc;
        f16* dst = (mat == 0) ? q_o : (mat == 1) ? k_o : v_o;
        f16* scr = &lds[w * 2304];
#pragma unroll
        for (int mt2 = 0; mt2 < 4; ++mt2) {
#pragma unroll
            for (int mtp = 0; mtp < 2; ++mtp) {
                const int mt = mt2*2 + mtp;
#pragma unroll
                for (int nt = 0; nt < 4; ++nt)
#pragma unroll
                    for (int rg = 0; rg < 4; ++rg)
                        scr[(mtp*16 + lq*4 + rg)*72 + nt*16 + lr] = (f16)acc[mt][nt][rg];
            }
            wfence();
#pragma unroll
            for (int i = 0; i < 4; ++i) {
                int row = (l >> 3) + i*8;
                f16x8 v = *(const f16x8*)&scr[row*72 + (l & 7)*8];
                int R = m0 + wr*128 + mt2*32 + row;
                if (R < MROWS) {
                    int bb = R / NTOK, nn = R - bb*NTOK;
                    *(f16x8*)&dst[((size_t)(bb*NH + hbase)*NTOK + nn)*HDIM + (l & 7)*8] = v;
                }
            }
            wfence();
        }
    } else {
#pragma unroll
        for (int mt = 0; mt < 8; ++mt)
#pragma unroll
            for (int rg = 0; rg < 4; ++rg) {
                int R = m0 + wr*128 + mt*16 + lq*4 + rg;
                if (R < MROWS) {
                    float* base = p_o + (size_t)R * EDIM + n0 + wc*64;
#pragma unroll
                    for (int nt = 0; nt < 4; ++nt) {
                        int c = nt*16 + lr;
                        base[c] = acc[mt][nt][rg] + bias[n0 + wc*64 + c];
                    }
                }
            }
    }
}

// ---------------------------------------------------------------------------
// MFMA fused attention v6: Kle [272][128] and Gt [32][256] XOR-swizzled
// (col ^= (row&7)<<3) — the round-10 "pad-stride" layouts (104/232) were
// 8-way bank-conflicted on every ds_read_b128 (stride ≡ 20 dw mod 32).
// Templates arrive pre-swizzled from prep_all; staging is linear copies.
// ---------------------------------------------------------------------------
#define SKE 128
#define SVT 320
#define SGT 256
#define SWS 72
#define ATHR 832

__global__ __launch_bounds__(ATHR, 1) void attn_mfma(
    const f16* __restrict__ q_ws, const f16* __restrict__ k_ws,
    const f16* __restrict__ v_ws,
    const float* __restrict__ rvv, const float* __restrict__ rvh,
    const f16* __restrict__ gA, const f16* __restrict__ gt_buf,
    f16* __restrict__ o_ws)
{
    __shared__ f16 Kle[272*SKE];     // 69632 B
    __shared__ f16 Vt[64*SVT];       // 40960 B
    __shared__ f16 Gt[32*SGT];       // 16384 B
    __shared__ f16 WSh[13*16*SWS];   // 29952 B  (total 156928 B)

    const int tid = threadIdx.x;
    const int w = tid >> 6, l = tid & 63;
    const int lr = l & 15, lq = l >> 4;
    const int bh = blockIdx.x;
    const int b = bh / NH, h = bh - b * NH;
    const f16* Qp = q_ws + (size_t)bh * NTOK * HDIM;
    const f16* Kp = k_ws + (size_t)bh * NTOK * HDIM;
    const f16* Vp = v_ws + (size_t)bh * NTOK * HDIM;
    f16* wsh = &WSh[w * 16 * SWS];

    // ---- Kle staging: K rows from Kp (swizzle applied via source col),
    //      everything else linear from the pre-swizzled template ----
    for (int idx = tid; idx < 272*16; idx += ATHR) {
        int row = idx >> 4, cs8 = (idx & 15) << 3;
        f16x8 v;
        if (row < NTOK && cs8 < 64) {
            int c8 = cs8 ^ ((row & 7) << 3);
            v = *(const f16x8*)(Kp + row*64 + c8);
        } else {
            v = *(const f16x8*)(gA + row*SKE + cs8);
        }
        *(f16x8*)&Kle[row*SKE + cs8] = v;
    }
    // ---- Gt: linear copy of pre-swizzled template ----
    for (int idx = tid; idx < 32*32; idx += ATHR) {
        int off = idx * 8;
        *(f16x8*)&Gt[off] = *(const f16x8*)(gt_buf + off);
    }
    // ---- Vt transpose staging (unchanged; already conflict-tolerable) ----
    for (int idx = tid; idx < 8*SVT; idx += ATHR) {
        int dlow = idx & 7, k = idx >> 3;
        int kx = k ^ (dlow << 3);
        bool isV = (k < NTOK), isA = (k >= 208 && k < 238), isB = (k >= 238 && k < 268);
#pragma unroll
        for (int e = 0; e < 8; ++e) {
            int d = (e << 3) + dlow;
            f16 val = (f16)0.f;
            if (isV)      val = Vp[k*64 + d];
            else if (isA) val = (f16)rvv[(k-208)*64 + d];
            else if (isB) val = (f16)rvh[(k-238)*64 + d];
            Vt[d*SVT + kx] = val;
        }
    }
    __syncthreads();

    const int src0 = ((l >> 4) & 1) * 32 + lr;
    const int src1 = src0 + 16;

    {
        const int tt = w;
        const int i0 = tt * 16;
        const int iq = i0 + lr;
        const int iqc = (iq > 196) ? 196 : iq;
        const f16* qsrc = Qp + iqc*64 + lq*8;
        f16x8 qf0 = *(const f16x8*)qsrc;
        f16x8 qf1 = *(const f16x8*)(qsrc + 32);

        const int sw = (lr & 7) << 3;   // Kle/Gt row is ct*16+lr -> key = lr&7

        __builtin_amdgcn_s_setprio(1);
        f32x4 pacc[4];
#pragma unroll
        for (int ct = 0; ct < 4; ++ct) {
            f32x4 a; a[0]=0.f; a[1]=0.f; a[2]=0.f; a[3]=0.f;
            const int krow = (13+ct)*16 + lr;
            f16x8 kf0 = *(f16x8*)&Kle[krow*SKE + ((lq*8) ^ sw)];
            f16x8 kf1 = *(f16x8*)&Kle[krow*SKE + ((32 + lq*8) ^ sw)];
            a = __builtin_amdgcn_mfma_f32_16x16x32_f16(kf0, qf0, a, 0, 0, 0);
            a = __builtin_amdgcn_mfma_f32_16x16x32_f16(kf1, qf1, a, 0, 0, 0);
            pacc[ct] = a;
        }
        __builtin_amdgcn_s_setprio(0);
#pragma unroll
        for (int ct = 0; ct < 4; ++ct)
#pragma unroll
            for (int rg = 0; rg < 4; ++rg)
                wsh[lr*SWS + ct*16 + lq*4 + rg] = (f16)pacc[ct][rg];
        wfence();

        int id_ = 0, ih_ = 0;
        const bool qcls = (iq == 0);
        if (iq > 0) { unsigned v = div14((unsigned)(iq-1)); id_ = (int)v; ih_ = (iq-1) - (int)v*14; }
        f16x8 qcf;
#pragma unroll
        for (int e = 0; e < 8; ++e) {
            int g = lq*8 + e;
            int toff;
            if (g < 14)       toff = qcls ? 0 : (g - id_ + 15);
            else if (g == 14) toff = 0;
            else if (g == 15) toff = 63;
            else if (g < 30)  toff = qcls ? 32 : (32 + (g-16) - ih_ + 15);
            else if (g == 30) toff = 32;
            else              toff = 63;
            qcf[e] = wsh[lr*SWS + toff];
        }

        f32x4 acc[13];
        __builtin_amdgcn_s_setprio(1);
#pragma unroll
        for (int ct = 0; ct < 13; ++ct) {
            f32x4 a; a[0]=0.f; a[1]=0.f; a[2]=0.f; a[3]=0.f;
            const int krow = ct*16 + lr;
            f16x8 kf0 = *(f16x8*)&Kle[krow*SKE + ((lq*8) ^ sw)];
            f16x8 kf1 = *(f16x8*)&Kle[krow*SKE + ((32 + lq*8) ^ sw)];
            f16x8 gf  = *(f16x8*)&Kle[krow*SKE + ((64 + lq*8) ^ sw)];
            a = __builtin_amdgcn_mfma_f32_16x16x32_f16(kf0, qf0, a, 0, 0, 0);
            a = __builtin_amdgcn_mfma_f32_16x16x32_f16(kf1, qf1, a, 0, 0, 0);
            a = __builtin_amdgcn_mfma_f32_16x16x32_f16(gf,  qcf, a, 0, 0, 0);
            acc[ct] = a;
        }
        __builtin_amdgcn_s_setprio(0);

#pragma unroll
        for (int rg = 0; rg < 4; ++rg)
            if (lq*4 + rg > 4) acc[12][rg] = -1e30f;

        float m = -1e30f;
#pragma unroll
        for (int ct = 0; ct < 13; ++ct)
#pragma unroll
            for (int rg = 0; rg < 4; ++rg) m = fmaxf(m, acc[ct][rg]);
        m = fmaxf(m, __shfl_xor(m, 16));
        m = fmaxf(m, __shfl_xor(m, 32));
        const float C1 = 0.125f * 1.44269504088896f;
        const float nm = -m * C1;
        float ssum = 0.f;
#pragma unroll
        for (int ct = 0; ct < 13; ++ct)
#pragma unroll
            for (int rg = 0; rg < 4; ++rg) {
                float p = exp2f(fmaf(acc[ct][rg], C1, nm));
                acc[ct][rg] = p; ssum += p;
            }
        ssum += __shfl_xor(ssum, 16);
        ssum += __shfl_xor(ssum, 32);
        const float inv = 1.f / ssum;
        const float pn00 = acc[0][0] * inv;

        unsigned pk[13][2];
#pragma unroll
        for (int ct = 0; ct < 13; ++ct) {
            union { f16x4 hh; unsigned u[2]; } t;
            t.hh[0] = (f16)(acc[ct][0] * inv);
            t.hh[1] = (f16)(acc[ct][1] * inv);
            t.hh[2] = (f16)(acc[ct][2] * inv);
            t.hh[3] = (f16)(acc[ct][3] * inv);
            pk[ct][0] = t.u[0]; pk[ct][1] = t.u[1];
        }

        f16x8 pa[7];
#pragma unroll
        for (int kc = 0; kc < 7; ++kc) {
            const int ctA = 2*kc;
            const int ctB = (kc == 6) ? 12 : 2*kc + 1;
            unsigned A0 = (unsigned)__shfl((int)pk[ctA][0], src0);
            unsigned A1 = (unsigned)__shfl((int)pk[ctA][1], src0);
            unsigned A2 = (unsigned)__shfl((int)pk[ctA][0], src1);
            unsigned A3 = (unsigned)__shfl((int)pk[ctA][1], src1);
            unsigned B0 = (unsigned)__shfl((int)pk[ctB][0], src0);
            unsigned B1 = (unsigned)__shfl((int)pk[ctB][1], src0);
            unsigned B2 = (unsigned)__shfl((int)pk[ctB][0], src1);
            unsigned B3 = (unsigned)__shfl((int)pk[ctB][1], src1);
            bool hiHalf = (lq >= 2);
            union { unsigned u[4]; f16x8 v; } f;
            f.u[0] = hiHalf ? B0 : A0;
            f.u[1] = hiHalf ? B1 : A1;
            f.u[2] = hiHalf ? B2 : A2;
            f.u[3] = hiHalf ? B3 : A3;
            if (kc == 6 && hiHalf) { f.u[0]=0; f.u[1]=0; f.u[2]=0; f.u[3]=0; }
            pa[kc] = f.v;
        }

        f32x4 gacc[2];
#pragma unroll
        for (int ct = 0; ct < 2; ++ct) { gacc[ct][0]=0.f; gacc[ct][1]=0.f; gacc[ct][2]=0.f; gacc[ct][3]=0.f; }
        __builtin_amdgcn_s_setprio(1);
#pragma unroll
        for (int kc = 0; kc < 7; ++kc) {
#pragma unroll
            for (int ct = 0; ct < 2; ++ct) {
                f16x8 gf = *(f16x8*)&Gt[(ct*16 + lr)*SGT + ((kc*32 + lq*8) ^ sw)];
                gacc[ct] = __builtin_amdgcn_mfma_f32_16x16x32_f16(pa[kc], gf, gacc[ct], 0, 0, 0);
            }
        }
        __builtin_amdgcn_s_setprio(0);

#pragma unroll
        for (int z = 0; z < 2; ++z) {
            int zi = z*64 + l;
            int zr = zi >> 3, zc = (zi & 7) << 3;
            f16x8 zz;
#pragma unroll
            for (int e = 0; e < 8; ++e) zz[e] = (f16)0.f;
            *(f16x8*)&wsh[zr*SWS + zc] = zz;
        }
        wfence();
#pragma unroll
        for (int rg = 0; rg < 4; ++rg) {
            int il = lq*4 + rg;
            int is_ = i0 + il;
            if (lr < 14 && is_ > 0) {
                unsigned v = div14((unsigned)(is_-1));
                int id2 = (int)v, ih2 = (is_-1) - (int)v*14;
                wsh[il*SWS + (lr - id2 + 15)]      = (f16)gacc[0][rg];
                wsh[il*SWS + 30 + (lr - ih2 + 15)] = (f16)gacc[1][rg];
            }
        }
        if (lq == 0 && !(i0 == 0 && lr == 0)) {
            wsh[lr*SWS + 0]  = (f16)pn00;
            wsh[lr*SWS + 30] = (f16)pn00;
        }
        if (i0 == 0) {
            float sv = (lq == 0) ? gacc[0][0] : 0.f;
            float sh = (lq == 0) ? gacc[1][0] : 0.f;
            sv += __shfl_xor(sv, 1); sv += __shfl_xor(sv, 2);
            sv += __shfl_xor(sv, 4); sv += __shfl_xor(sv, 8);
            sh += __shfl_xor(sh, 1); sh += __shfl_xor(sh, 2);
            sh += __shfl_xor(sh, 4); sh += __shfl_xor(sh, 8);
            if (l == 0) {
                wsh[0]  = (f16)(sv + pn00);
                wsh[30] = (f16)(sh + pn00);
            }
        }
        wfence();

        f16x8 sfr[2];
#pragma unroll
        for (int kc2 = 0; kc2 < 2; ++kc2)
            sfr[kc2] = *(f16x8*)&wsh[lr*SWS + kc2*32 + lq*8];

        f32x4 oacc[4];
#pragma unroll
        for (int ct = 0; ct < 4; ++ct) { oacc[ct][0]=0.f; oacc[ct][1]=0.f; oacc[ct][2]=0.f; oacc[ct][3]=0.f; }
        __builtin_amdgcn_s_setprio(1);
#pragma unroll
        for (int kc = 0; kc < 7; ++kc) {
#pragma unroll
            for (int ct = 0; ct < 4; ++ct) {
                f16x8 vf = *(f16x8*)&Vt[(ct*16 + lr)*SVT + ((kc*32 + lq*8) ^ sw)];
                oacc[ct] = __builtin_amdgcn_mfma_f32_16x16x32_f16(pa[kc], vf, oacc[ct], 0, 0, 0);
            }
        }
#pragma unroll
        for (int kc2 = 0; kc2 < 2; ++kc2) {
#pragma unroll
            for (int ct = 0; ct < 4; ++ct) {
                f16x8 vf = *(f16x8*)&Vt[(ct*16 + lr)*SVT + ((208 + kc2*32 + lq*8) ^ sw)];
                oacc[ct] = __builtin_amdgcn_mfma_f32_16x16x32_f16(sfr[kc2], vf, oacc[ct], 0, 0, 0);
            }
        }
        __builtin_amdgcn_s_setprio(0);

#pragma unroll
        for (int ct = 0; ct < 4; ++ct)
#pragma unroll
            for (int rg = 0; rg < 4; ++rg) {
                int io = i0 + lq*4 + rg;
                if (io < NTOK) {
                    int d = ct*16 + lr;
                    o_ws[((size_t)(b * NTOK + io) * NH + h) * HDIM + d] = (f16)oacc[ct][rg];
                }
            }
    }
}

extern "C" void kernel_launch(void* const* d_in, const int* in_sizes, int n_in,
                              void* d_out, int out_size, void* d_ws, size_t ws_size,
                              hipStream_t stream)
{
    const float* x     = (const float*)d_in[0];
    const float* wq    = (const float*)d_in[1];
    const float* wk    = (const float*)d_in[2];
    const float* wv    = (const float*)d_in[3];
    const float* wproj = (const float*)d_in[4];
    const float* bproj = (const float*)d_in[5];
    const float* rkv   = (const float*)d_in[6];
    const float* rkh   = (const float*)d_in[7];
    const float* rvv   = (const float*)d_in[8];
    const float* rvh   = (const float*)d_in[9];

    f16* ws = (f16*)d_ws;
    const size_t sz = (size_t)MROWS * EDIM;
    f16* xh    = ws;
    f16* qh    = xh + sz;
    f16* kh    = qh + sz;
    f16* vh    = kh + sz;
    f16* oh    = vh + sz;
    f16* wqkvT = oh + sz;                          // 3*768*768
    f16* wpT   = wqkvT + (size_t)3*EDIM*EDIM;      // 768*768
    f16* gA    = wpT   + (size_t)EDIM*EDIM;        // 272*128 (pre-swizzled)
    f16* gtb   = gA    + 272*128;                  // 32*256  (pre-swizzled)

    prep_all<<<5336, 256, 0, stream>>>(x, wq, wk, wv, wproj, rkv, rkh,
                                       xh, wqkvT, wpT, gA, gtb);
    gemm256 <<<50*9, 512, 0, stream>>>(xh, wqkvT, qh, kh, vh,
                                       nullptr, nullptr, 0, 9);
    attn_mfma<<<NB * NH, ATHR, 0, stream>>>(qh, kh, vh,
                                            rvv, rvh, gA, gtb, oh);
    gemm256 <<<50*3, 512, 0, stream>>>(oh, wpT, nullptr, nullptr, nullptr,
                                       (float*)d_out, bproj, 1, 3);
}